// Round 20
// baseline (403.849 us; speedup 1.0000x reference)
//
#include <hip/hip_runtime.h>
#include <hip/hip_bf16.h>
#include <cstdint>
#include <cstddef>

using u16 = unsigned short;
typedef short short8 __attribute__((ext_vector_type(8)));
typedef short short4v __attribute__((ext_vector_type(4)));
typedef float f32x4  __attribute__((ext_vector_type(4)));

#define DEV static __device__ __forceinline__

DEV float b2f(u16 u){ union{ unsigned i; float f; } v; v.i = ((unsigned)u)<<16; return v.f; }
DEV u16 f2b(float f){
  unsigned i = __builtin_bit_cast(unsigned, f);
  unsigned r = (i + 0x7FFFu + ((i>>16)&1u)) >> 16;
  return (u16)r;
}
DEV f32x4 mfma16(short8 a, short8 b, f32x4 c){
  return __builtin_amdgcn_mfma_f32_16x16x32_bf16(a, b, c, 0, 0, 0);
}
// LDS-only barrier: waits own LDS ops, then s_barrier. Global loads stay in
// flight across it (their results guarded by compiler register-dep vmcnt).
DEV void barrier_lgkm(){
  asm volatile("s_waitcnt lgkmcnt(0)" ::: "memory");
  __builtin_amdgcn_s_barrier();
}

constexpr int Bn=64, Sn=31, Tn=2048, Cn=512, Hn=8;
constexpr int Rn=Bn*Sn;           // 1984
constexpr int BHn=Bn*Hn;          // 512
constexpr int HRn=Hn*Sn;          // 248
constexpr float EPSf=1e-5f;
constexpr float INV_SCALE=0.04419417382415922f;   // 1/sqrt(512)

__global__ void k_badorder(float* out){
  if(threadIdx.x==0) out[0]=2000.f;
}

// ------- merged: 10 weight fp32->bf16 segments (blocks 0..1535) + bn1 partial (1536..1567) ----
struct Src10 { const float* p[10]; };
__global__ __launch_bounds__(256) void k_cvtbn(Src10 s, u16* __restrict__ dst,
    const float* __restrict__ q, float* __restrict__ ps, float* __restrict__ psq){
  int bid=blockIdx.x;
  if(bid<1536){
    int i = bid*256 + threadIdx.x;          // n8 index, total 393216
    int seg, j=i;
    if(j>=196608){
      if(j>=327680){ if(j>=360448){seg=9;j-=360448;} else {seg=8;j-=327680;} }
      else if(j>=262144){seg=7;j-=262144;}
      else {seg=6;j-=196608;}
    } else { seg=j>>15; j&=32767; }
    const float* src=s.p[seg];
    f32x4 a=*(const f32x4*)&src[(size_t)j*8];
    f32x4 b=*(const f32x4*)&src[(size_t)j*8+4];
    short8 o;
    #pragma unroll
    for(int qq=0;qq<4;++qq){ o[qq]=(short)f2b(a[qq]); o[4+qq]=(short)f2b(b[qq]); }
    *(short8*)&dst[(size_t)i*8]=o;
  } else {
    int bb=bid-1536;                        // 0..31
    int c = (bb&1)*256 + threadIdx.x;
    int r0 = (bb>>1)*124;
    float sum=0.f, sq=0.f;
    for(int r=r0;r<r0+124;++r){ float v=q[(size_t)r*Cn+c]; sum+=v; sq+=v*v; }
    ps [(bb>>1)*Cn+c]=sum;
    psq[(bb>>1)*Cn+c]=sq;
  }
}

__global__ __launch_bounds__(512) void k_bn1_final(const float* __restrict__ ps,
    const float* __restrict__ psq, const float* __restrict__ g,
    const float* __restrict__ b, float* __restrict__ scale, float* __restrict__ shift){
  int c = threadIdx.x;
  float s=0.f, sq=0.f;
  for(int i=0;i<16;++i){ s+=ps[i*Cn+c]; sq+=psq[i*Cn+c]; }
  float m = s/(float)Rn;
  float v = sq/(float)Rn - m*m;
  float rs = rsqrtf(v+EPSf);
  float sc = rs*g[c];
  scale[c]=sc; shift[c]=b[c]-m*sc;
}

// ---------------- fused BN + QKV projections (grid.z selects q/k/v) ------------
__global__ __launch_bounds__(256) void k_qkv(
    const float* __restrict__ q, const float* __restrict__ scale,
    const float* __restrict__ shift,
    const u16* __restrict__ W0, const u16* __restrict__ W1, const u16* __restrict__ W2,
    u16* __restrict__ o0, u16* __restrict__ o1v, u16* __restrict__ o2v)
{
  __shared__ u16 As[64][72];
  __shared__ u16 Ws[64][72];
  const int z=blockIdx.z;
  const u16* W = (z==0)?W0:((z==1)?W1:W2);
  u16* out     = (z==0)?o0:((z==1)?o1v:o2v);
  const int t=threadIdx.x, w=t>>6, l=t&63;
  const int m0=blockIdx.x*64, n0=blockIdx.y*64;
  const int lr=l&15, lk=(l>>4)*8;
  f32x4 zero={0.f,0.f,0.f,0.f};
  f32x4 acc[4];
  #pragma unroll
  for(int i=0;i<4;++i) acc[i]=zero;
  const int row0=t>>3, c8=(t&7)*8;
  for(int k0=0;k0<Cn;k0+=64){
    f32x4 sc0=*(const f32x4*)&scale[k0+c8], sc1=*(const f32x4*)&scale[k0+c8+4];
    f32x4 sh0=*(const f32x4*)&shift[k0+c8], sh1=*(const f32x4*)&shift[k0+c8+4];
    f32x4 x00=*(const f32x4*)&q[(size_t)(m0+row0   )*Cn+k0+c8];
    f32x4 x01=*(const f32x4*)&q[(size_t)(m0+row0   )*Cn+k0+c8+4];
    f32x4 x10=*(const f32x4*)&q[(size_t)(m0+32+row0)*Cn+k0+c8];
    f32x4 x11=*(const f32x4*)&q[(size_t)(m0+32+row0)*Cn+k0+c8+4];
    short8 a0,a1;
    #pragma unroll
    for(int j=0;j<4;++j){
      a0[j]  =(short)f2b(fmaf(x00[j],sc0[j],sh0[j]));
      a0[4+j]=(short)f2b(fmaf(x01[j],sc1[j],sh1[j]));
      a1[j]  =(short)f2b(fmaf(x10[j],sc0[j],sh0[j]));
      a1[4+j]=(short)f2b(fmaf(x11[j],sc1[j],sh1[j]));
    }
    short8 w0=*(const short8*)&W[(size_t)(n0+row0   )*Cn + k0 + c8];
    short8 w1=*(const short8*)&W[(size_t)(n0+32+row0)*Cn + k0 + c8];
    __syncthreads();
    *(short8*)&As[row0   ][c8]=a0;
    *(short8*)&As[32+row0][c8]=a1;
    *(short8*)&Ws[row0   ][c8]=w0;
    *(short8*)&Ws[32+row0][c8]=w1;
    __syncthreads();
    #pragma unroll
    for(int ks=0;ks<64;ks+=32){
      short8 af=*(const short8*)&As[w*16+lr][ks+lk];
      #pragma unroll
      for(int nf=0;nf<4;++nf){
        short8 bf=*(const short8*)&Ws[nf*16+lr][ks+lk];
        acc[nf]=mfma16(af,bf,acc[nf]);
      }
    }
  }
  const int r0=w*16+(l>>4)*4;
  #pragma unroll
  for(int nf=0;nf<4;++nf){
    const int n=n0+nf*16+lr;
    #pragma unroll
    for(int r=0;r<4;++r){
      const int m=m0+r0+r;
      out[(size_t)m*Cn+n]=f2b(acc[nf][r]);
    }
  }
}

// ---------------- generic 64x64-tile GEMM: out = A * W^T (+bias)(+res) ----------------
template<bool F32OUT, bool RES32>
__global__ __launch_bounds__(256) void k_gemm64(
    const u16* __restrict__ A, const u16* __restrict__ W,
    const float* __restrict__ bias, const void* __restrict__ res,
    void* __restrict__ outv, int M, int N, int K)
{
  __shared__ u16 As[64][72];
  __shared__ u16 Ws[64][72];
  const int t=threadIdx.x, w=t>>6, l=t&63;
  const int m0=blockIdx.x*64, n0=blockIdx.y*64;
  const int lr=l&15, lk=(l>>4)*8;
  f32x4 zero={0.f,0.f,0.f,0.f};
  f32x4 acc[4];
  #pragma unroll
  for(int i=0;i<4;++i) acc[i]=zero;
  const int row0=t>>3, c8=(t&7)*8;
  for(int k0=0;k0<K;k0+=64){
    short8 a0=*(const short8*)&A[(size_t)(m0+row0   )*K + k0 + c8];
    short8 a1=*(const short8*)&A[(size_t)(m0+32+row0)*K + k0 + c8];
    short8 w0=*(const short8*)&W[(size_t)(n0+row0   )*K + k0 + c8];
    short8 w1=*(const short8*)&W[(size_t)(n0+32+row0)*K + k0 + c8];
    __syncthreads();
    *(short8*)&As[row0   ][c8]=a0;
    *(short8*)&As[32+row0][c8]=a1;
    *(short8*)&Ws[row0   ][c8]=w0;
    *(short8*)&Ws[32+row0][c8]=w1;
    __syncthreads();
    #pragma unroll
    for(int ks=0;ks<64;ks+=32){
      short8 af=*(const short8*)&As[w*16+lr][ks+lk];
      #pragma unroll
      for(int nf=0;nf<4;++nf){
        short8 bf=*(const short8*)&Ws[nf*16+lr][ks+lk];
        acc[nf]=mfma16(af,bf,acc[nf]);
      }
    }
  }
  const int r0=w*16+(l>>4)*4;
  #pragma unroll
  for(int nf=0;nf<4;++nf){
    const int n=n0+nf*16+lr;
    float bv = bias? bias[n] : 0.f;
    #pragma unroll
    for(int r=0;r<4;++r){
      const int m=m0+r0+r;
      float vv=acc[nf][r]+bv;
      if(res){
        if(RES32) vv += ((const float*)res)[(size_t)m*N+n];
        else      vv += b2f(((const u16*)res)[(size_t)m*N+n]);
      }
      if(F32OUT) ((float*)outv)[(size_t)m*N+n]=vv;
      else       ((u16*)outv)[(size_t)m*N+n]=f2b(vv);
    }
  }
}

// ---------------- SA energy: per (b,h) 31x31 = q[31x64] * k[31x64]^T ----------------
__global__ __launch_bounds__(64) void k_energy1(const u16* __restrict__ q,
    const u16* __restrict__ k, float* __restrict__ e1){
  __shared__ u16 qs[32][72];
  __shared__ u16 ks_[32][72];
  const int bh=blockIdx.x, b=bh>>3, h=bh&7;
  const int t=threadIdx.x, l=t;
  #pragma unroll
  for(int i=0;i<4;++i){
    int flat=i*64+t; int row=flat>>3, c8=(flat&7)*8;
    short8 zq={0,0,0,0,0,0,0,0}, zk={0,0,0,0,0,0,0,0};
    if(row<31){
      zq=*(const short8*)&q[(size_t)(b*31+row)*Cn + h*64 + c8];
      zk=*(const short8*)&k[(size_t)(b*31+row)*Cn + h*64 + c8];
    }
    *(short8*)&qs [row][c8]=zq;
    *(short8*)&ks_[row][c8]=zk;
  }
  __syncthreads();
  const int lr=l&15, lk=(l>>4)*8;
  f32x4 zero={0.f,0.f,0.f,0.f};
  f32x4 acc[2][2];
  acc[0][0]=zero; acc[0][1]=zero; acc[1][0]=zero; acc[1][1]=zero;
  #pragma unroll
  for(int ks=0;ks<64;ks+=32){
    short8 a0=*(const short8*)&qs [lr   ][ks+lk];
    short8 a1=*(const short8*)&qs [16+lr][ks+lk];
    short8 b0=*(const short8*)&ks_[lr   ][ks+lk];
    short8 b1=*(const short8*)&ks_[16+lr][ks+lk];
    acc[0][0]=mfma16(a0,b0,acc[0][0]);
    acc[0][1]=mfma16(a0,b1,acc[0][1]);
    acc[1][0]=mfma16(a1,b0,acc[1][0]);
    acc[1][1]=mfma16(a1,b1,acc[1][1]);
  }
  const int r0=(l>>4)*4;
  #pragma unroll
  for(int i=0;i<2;++i)
    #pragma unroll
    for(int j=0;j<2;++j)
      #pragma unroll
      for(int r=0;r<4;++r){
        int qi=i*16+r0+r, ki=j*16+lr;
        if(qi<31 && ki<31) e1[(size_t)bh*961 + qi*31 + ki]=acc[i][j][r];
      }
}

// ---------------- BN over (B,H) on energy positions p=0..960 ----------------
__global__ __launch_bounds__(256) void k_bn2_partial(const float* __restrict__ e1,
    float* __restrict__ ps, float* __restrict__ psq){
  int p=blockIdx.x*256+threadIdx.x;
  if(p>=961) return;
  int r0=blockIdx.y*64;
  float s=0.f, sq=0.f;
  for(int r=r0;r<r0+64;++r){ float v=e1[(size_t)r*961+p]; s+=v; sq+=v*v; }
  ps [blockIdx.y*961+p]=s;
  psq[blockIdx.y*961+p]=sq;
}
__global__ __launch_bounds__(1024) void k_bn2_final(const float* __restrict__ ps,
    const float* __restrict__ psq, float* __restrict__ mu2, float* __restrict__ rstd2){
  int p=threadIdx.x; if(p>=961) return;
  float s=0.f, sq=0.f;
  for(int i=0;i<8;++i){ s+=ps[i*961+p]; sq+=psq[i*961+p]; }
  float m=s/512.f, v=sq/512.f-m*m;
  mu2[p]=m; rstd2[p]=rsqrtf(v+EPSf);
}

// ---------------- fused SA softmax (BN2-applied) + PV, one block per (b,h) --------
__global__ __launch_bounds__(64) void k_smpv(const float* __restrict__ e1,
    const float* __restrict__ mu2, const float* __restrict__ rstd2,
    const float* __restrict__ g2, const float* __restrict__ bb2,
    const u16* __restrict__ v, u16* __restrict__ o1){
  __shared__ u16 at[32][40];   // softmax probs, bf16
  __shared__ u16 vs[64][40];   // transposed V: vs[dh][kv]
  const int bh=blockIdx.x, b=bh>>3, h=bh&7;
  const int l=threadIdx.x;
  for(int kv=0;kv<31;++kv) vs[l][kv]=v[(size_t)(b*31+kv)*Cn + h*64 + l];
  vs[l][31]=0;
  if(l<31){
    const float* er=e1+(size_t)bh*961 + l*31;
    float lg[31]; float mx=-1e30f;
    #pragma unroll
    for(int kk=0;kk<31;++kk){
      int p=l*31+kk;
      float en=(er[kk]-mu2[p])*rstd2[p]*g2[p]+bb2[p];
      lg[kk]=en*INV_SCALE;
      mx=fmaxf(mx,lg[kk]);
    }
    float s=0.f;
    #pragma unroll
    for(int kk=0;kk<31;++kk){ lg[kk]=__expf(lg[kk]-mx); s+=lg[kk]; }
    float inv=1.f/s;
    #pragma unroll
    for(int kk=0;kk<31;++kk) at[l][kk]=f2b(lg[kk]*inv);
    at[l][31]=0;
  } else if(l==31){
    #pragma unroll
    for(int kk=0;kk<32;++kk) at[31][kk]=0;
  }
  __syncthreads();
  const int lr=l&15, lk=(l>>4)*8;
  f32x4 zero={0.f,0.f,0.f,0.f};
  f32x4 acc[2][4];
  #pragma unroll
  for(int i=0;i<2;++i)
    #pragma unroll
    for(int nf=0;nf<4;++nf) acc[i][nf]=zero;
  short8 a0=*(const short8*)&at[lr   ][lk];
  short8 a1=*(const short8*)&at[16+lr][lk];
  #pragma unroll
  for(int nf=0;nf<4;++nf){
    short8 bf=*(const short8*)&vs[nf*16+lr][lk];
    acc[0][nf]=mfma16(a0,bf,acc[0][nf]);
    acc[1][nf]=mfma16(a1,bf,acc[1][nf]);
  }
  const int r0=(l>>4)*4;
  #pragma unroll
  for(int i=0;i<2;++i)
    #pragma unroll
    for(int nf=0;nf<4;++nf)
      #pragma unroll
      for(int r=0;r<4;++r){
        int qi=i*16+r0+r;
        if(qi<31){
          int dh=nf*16+lr;
          o1[(size_t)(b*31+qi)*Cn + h*64 + dh]=f2b(acc[i][nf][r]);
        }
      }
}

// ---------------- row LayerNorm (optionally + SiLU), wave per row ----------------
template<int Wd, bool SILU>
__global__ __launch_bounds__(256) void k_ln(const u16* __restrict__ x,
    const float* __restrict__ g, const float* __restrict__ b, u16* __restrict__ out){
  const int w=threadIdx.x>>6, l=threadIdx.x&63;
  const int row=blockIdx.x*4+w;
  constexpr int NC=Wd/512;
  float v[NC*8];
  #pragma unroll
  for(int i=0;i<NC;++i){
    short8 s=*(const short8*)&x[(size_t)row*Wd + i*512 + l*8];
    #pragma unroll
    for(int j=0;j<8;++j) v[i*8+j]=b2f((u16)s[j]);
  }
  float s1=0.f, s2=0.f;
  #pragma unroll
  for(int e=0;e<NC*8;++e){ s1+=v[e]; s2+=v[e]*v[e]; }
  #pragma unroll
  for(int off=1;off<64;off<<=1){ s1+=__shfl_xor(s1,off,64); s2+=__shfl_xor(s2,off,64); }
  float m=s1/(float)Wd, var=s2/(float)Wd-m*m, rs=rsqrtf(var+EPSf);
  #pragma unroll
  for(int i=0;i<NC;++i){
    short8 o;
    #pragma unroll
    for(int j=0;j<8;++j){
      int c=i*512+l*8+j;
      float y=(v[i*8+j]-m)*rs*g[c]+b[c];
      if(SILU) y=y/(1.f+__expf(-y));
      o[j]=(short)f2b(y);
    }
    *(short8*)&out[(size_t)row*Wd + i*512 + l*8]=o;
  }
}

// ---------------- CA step 1: qk = q2_h (31x64) . Wk_h (64x512), Wk bf16 ----
__global__ __launch_bounds__(256) void k_qk(const u16* __restrict__ q2,
    const u16* __restrict__ Wk, u16* __restrict__ qk){
  __shared__ u16 qs[32][72];
  __shared__ u16 bt[128][72];    // bt[c][d] = Wk[h*64+d][nc+c]
  const int bh=blockIdx.x, b=bh>>3, h=bh&7;
  const int t=threadIdx.x, w=t>>6, l=t&63;
  {
    int row=t>>3, c8=(t&7)*8;
    short8 z={0,0,0,0,0,0,0,0};
    if(row<31) z=*(const short8*)&q2[(size_t)(b*31+row)*Cn + h*64 + c8];
    *(short8*)&qs[row][c8]=z;
  }
  const int lr=l&15, lk=(l>>4)*8;
  const int r0=(l>>4)*4;
  for(int nc=0;nc<512;nc+=128){
    __syncthreads();
    #pragma unroll
    for(int i=0;i<4;++i){
      int g=i*256+t;             // 0..1023
      int d=g>>4, c8=(g&15)*8;
      short8 s=*(const short8*)&Wk[(size_t)(h*64+d)*Cn + nc + c8];
      #pragma unroll
      for(int jj=0;jj<8;++jj) bt[c8+jj][d]=(u16)s[jj];
    }
    __syncthreads();
    f32x4 zero={0.f,0.f,0.f,0.f};
    f32x4 acc[2][2];
    acc[0][0]=zero; acc[0][1]=zero; acc[1][0]=zero; acc[1][1]=zero;
    #pragma unroll
    for(int ks=0;ks<64;ks+=32){
      short8 a0=*(const short8*)&qs[lr   ][ks+lk];
      short8 a1=*(const short8*)&qs[16+lr][ks+lk];
      #pragma unroll
      for(int nf=0;nf<2;++nf){
        short8 bf=*(const short8*)&bt[w*32+nf*16+lr][ks+lk];
        acc[0][nf]=mfma16(a0,bf,acc[0][nf]);
        acc[1][nf]=mfma16(a1,bf,acc[1][nf]);
      }
    }
    #pragma unroll
    for(int i=0;i<2;++i)
      #pragma unroll
      for(int nf=0;nf<2;++nf)
        #pragma unroll
        for(int r=0;r<4;++r){
          int qi=i*16+r0+r;
          if(qi<31)
            qk[((size_t)b*HRn + h*31 + qi)*Cn + nc + w*32 + nf*16 + lr]=f2b(acc[i][nf][r]);
        }
  }
}

// ---------------- CA step 2: e2(fp32) = qk . ctx^T ; exports ctxb bf16,
//                  P=exp(e2*s) bf16 into pb, partial denoms into psca.
//                  XCD-swizzled + LDS-only barriers + 2-deep register pipeline. ----
__global__ __launch_bounds__(512) void k_e2big(const u16* __restrict__ qk,
    const float* __restrict__ ctx, float* __restrict__ e2, u16* __restrict__ ctxb,
    u16* __restrict__ pb, float* __restrict__ psca){
  __shared__ u16 As[256][72];
  __shared__ u16 Bs[128][72];
  // XCD swizzle (T1): nwg=1024, cpx=128; swz=(bid%8)*128+bid/8 (bijective)
  const int bid = blockIdx.x + 16*blockIdx.y;
  const int swz = (bid&7)*128 + (bid>>3);
  const int b   = swz>>4;
  const int tb  = (swz&15)*128;
  const int t=threadIdx.x, w=t>>6, l=t&63;
  const int lr=l&15, lk=(l>>4)*8;
  const int wr=(w>>1)*64, wc=(w&1)*64;
  f32x4 zero={0.f,0.f,0.f,0.f};
  f32x4 acc[4][4];
  #pragma unroll
  for(int i=0;i<4;++i)
    #pragma unroll
    for(int j=0;j<4;++j) acc[i][j]=zero;

  const int arow[4]={ (0*512+t)>>3, (1*512+t)>>3, (2*512+t)>>3, (3*512+t)>>3 };
  const int ac8=(t&7)*8;
  const int brow=t>>4, bc4=(t&15)*4;     // 512 threads -> rows 0..31 per i-chunk
  short8 aregA[4], aregB[4];
  f32x4  bregA[4], bregB[4];
  auto loadK=[&](int k0, short8 (&ar)[4], f32x4 (&br)[4]){
    #pragma unroll
    for(int i=0;i<4;++i){
      short8 z={0,0,0,0,0,0,0,0};
      if(arow[i]<HRn) z=*(const short8*)&qk[((size_t)b*HRn+arow[i])*Cn + k0 + ac8];
      ar[i]=z;
    }
    #pragma unroll
    for(int i=0;i<4;++i)
      br[i]=*(const f32x4*)&ctx[((size_t)b*Tn + tb + i*32+brow)*Cn + k0 + bc4];
  };
  auto writeK=[&](int k0, short8 (&ar)[4], f32x4 (&br)[4]){
    #pragma unroll
    for(int i=0;i<4;++i) *(short8*)&As[arow[i]][ac8]=ar[i];
    #pragma unroll
    for(int i=0;i<4;++i){
      short4v o;
      #pragma unroll
      for(int jj=0;jj<4;++jj) o[jj]=(short)f2b(br[i][jj]);
      *(short4v*)&Bs[i*32+brow][bc4]=o;
      *(short4v*)&ctxb[((size_t)b*Tn + tb + i*32+brow)*Cn + k0 + bc4]=o;
    }
  };
  auto mfmaK=[&](){
    #pragma unroll
    for(int ks=0;ks<64;ks+=32){
      short8 af[4], bf[4];
      #pragma unroll
      for(int i=0;i<4;++i){
        af[i]=*(const short8*)&As[wr+i*16+lr][ks+lk];
        bf[i]=*(const short8*)&Bs[wc+i*16+lr][ks+lk];
      }
      #pragma unroll
      for(int i=0;i<4;++i)
        #pragma unroll
        for(int j=0;j<4;++j)
          acc[i][j]=mfma16(af[i],bf[j],acc[i][j]);
    }
  };
  loadK(0, aregA, bregA);
  for(int k0=0;k0<512;k0+=128){
    // step A (k0): prefetch k0+64 into B, then consume A (its loads are 1 iter old)
    loadK(k0+64, aregB, bregB);
    barrier_lgkm();
    writeK(k0, aregA, bregA);
    barrier_lgkm();
    mfmaK();
    // step B (k0+64): prefetch k0+128 into A, consume B
    if(k0+128<512) loadK(k0+128, aregA, bregA);
    barrier_lgkm();
    writeK(k0+64, aregB, bregB);
    barrier_lgkm();
    mfmaK();
  }
  const int r0=(l>>4)*4;
  #pragma unroll
  for(int i=0;i<4;++i)
    #pragma unroll
    for(int r=0;r<4;++r){
      int rm=wr+i*16+r0+r;
      float psum=0.f;
      #pragma unroll
      for(int j=0;j<4;++j){
        float vv=acc[i][j][r];
        if(rm<HRn){
          size_t col = tb + wc + j*16 + lr;
          e2[((size_t)b*HRn+rm)*Tn + col]=vv;
          float p=__expf(vv*INV_SCALE);
          pb[((size_t)b*256+rm)*Tn + col]=f2b(p);
          psum+=p;
        }
      }
      // reduce over the 16 lanes (lr) that share this row
      psum+=__shfl_xor(psum,1,64);
      psum+=__shfl_xor(psum,2,64);
      psum+=__shfl_xor(psum,4,64);
      psum+=__shfl_xor(psum,8,64);
      if(rm<HRn && lr==0)
        psca[((size_t)b*HRn+rm)*32 + (tb>>7)*2 + (wc>>6)]=psum;
    }
}

// ---------------- reduce 32 partials per row -> denom st[row] ----------------
__global__ __launch_bounds__(256) void k_castred(const float* __restrict__ psca,
    float* __restrict__ st){
  int i=blockIdx.x*256+threadIdx.x;   // 0..15871
  if(i>=BHn*31) return;
  float s=0.f;
  #pragma unroll
  for(int j=0;j<32;++j) s+=psca[(size_t)i*32+j];
  st[i]=s;
}

// ---------------- CA step 3: o2t = P . ctxb, XCD-swizzled + LDS-only barriers
//                  + 2-deep register pipeline. ----
__global__ __launch_bounds__(512) void k_pv2(const u16* __restrict__ pb,
    const u16* __restrict__ ctxb, const float* __restrict__ st,
    u16* __restrict__ o2t){
  __shared__ u16 As[128][72];
  __shared__ u16 Bs[128][76];
  // XCD swizzle (T1): nwg=512, cpx=64; swz=(bid%8)*64+bid/8 (bijective)
  const int bid = blockIdx.x + 4*(blockIdx.y + 2*blockIdx.z);
  const int swz = (bid&7)*64 + (bid>>3);
  const int b   = swz>>3;
  const int m0  = ((swz>>2)&1)*128;
  const int n0  = (swz&3)*128;
  const int t=threadIdx.x, w=t>>6, l=t&63;
  const int lr=l&15, lk=(l>>4)*8;
  const int wm=(w>>2)*64, wn=(w&3)*32;
  f32x4 zero={0.f,0.f,0.f,0.f};
  f32x4 acc[4][2];
  #pragma unroll
  for(int i=0;i<4;++i){ acc[i][0]=zero; acc[i][1]=zero; }
  const int arow=t>>3, ac8=(t&7)*8;     // A staging (2 iters)
  const int bc=t&127, bq=(t>>7)*4;      // B staging: column bc, quads bq..bq+3
  short8 aregA[2], aregB[2];
  u16 bregA[16], bregB[16];
  auto loadK=[&](int kb, short8 (&ar)[2], u16 (&br)[16]){
    #pragma unroll
    for(int i=0;i<2;++i)
      ar[i]=*(const short8*)&pb[((size_t)b*256 + m0 + arow+i*64)*Tn + kb + ac8];
    #pragma unroll
    for(int i=0;i<4;++i){
      int kt0=(bq+i)*4;
      #pragma unroll
      for(int jj=0;jj<4;++jj)
        br[i*4+jj]=ctxb[((size_t)b*Tn + kb + kt0 + jj)*Cn + n0 + bc];
    }
  };
  auto writeK=[&](short8 (&ar)[2], u16 (&br)[16]){
    #pragma unroll
    for(int i=0;i<2;++i) *(short8*)&As[arow+i*64][ac8]=ar[i];
    #pragma unroll
    for(int i=0;i<4;++i){
      short4v o;
      #pragma unroll
      for(int jj=0;jj<4;++jj) o[jj]=(short)br[i*4+jj];
      *(short4v*)&Bs[bc][(bq+i)*4]=o;
    }
  };
  auto mfmaK=[&](){
    #pragma unroll
    for(int ks=0;ks<64;ks+=32){
      short8 af[4], bf[2];
      #pragma unroll
      for(int i=0;i<4;++i)
        af[i]=*(const short8*)&As[wm+i*16+lr][ks+lk];
      #pragma unroll
      for(int j=0;j<2;++j){
        const u16* p=&Bs[wn+j*16+lr][ks+lk];
        short4v lo=*(const short4v*)p;
        short4v hi=*(const short4v*)(p+4);
        short8 bb;
        #pragma unroll
        for(int jj=0;jj<4;++jj){ bb[jj]=lo[jj]; bb[4+jj]=hi[jj]; }
        bf[j]=bb;
      }
      #pragma unroll
      for(int i=0;i<4;++i)
        #pragma unroll
        for(int j=0;j<2;++j)
          acc[i][j]=mfma16(af[i],bf[j],acc[i][j]);
    }
  };
  loadK(0, aregA, bregA);
  for(int kb=0;kb<Tn;kb+=128){
    loadK(kb+64, aregB, bregB);
    barrier_lgkm();
    writeK(aregA, bregA);
    barrier_lgkm();
    mfmaK();
    if(kb+128<Tn) loadK(kb+128, aregA, bregA);
    barrier_lgkm();
    writeK(aregB, bregB);
    barrier_lgkm();
    mfmaK();
  }
  const int r0=(l>>4)*4;
  #pragma unroll
  for(int i=0;i<4;++i)
    #pragma unroll
    for(int j=0;j<2;++j)
      #pragma unroll
      for(int r=0;r<4;++r){
        int rm=m0+wm+i*16+r0+r;
        if(rm<HRn){
          float inv=1.f/st[(size_t)b*HRn+rm];
          o2t[((size_t)b*HRn+rm)*Cn + n0+wn+j*16+lr]=f2b(acc[i][j][r]*inv);
        }
      }
}

// ---------------- CA step 4: o2b = o2t_h (31x512) . Wv_h^T (64x512), Wv bf16 ------
__global__ __launch_bounds__(256) void k_o2proj(const u16* __restrict__ o2t,
    const u16* __restrict__ Wv, u16* __restrict__ o2b){
  __shared__ u16 As[32][72];
  __shared__ u16 Ws[64][72];
  const int bh=blockIdx.x, b=bh>>3, h=bh&7;
  const int t=threadIdx.x, w=t>>6, l=t&63;
  const int lr=l&15, lk=(l>>4)*8;
  f32x4 zero={0.f,0.f,0.f,0.f};
  f32x4 acc[2]; acc[0]=zero; acc[1]=zero;
  for(int k0=0;k0<512;k0+=64){
    __syncthreads();
    {
      int row=t>>3, c8=(t&7)*8;
      short8 z={0,0,0,0,0,0,0,0};
      if(row<31) z=*(const short8*)&o2t[((size_t)b*HRn + h*31 + row)*Cn + k0 + c8];
      *(short8*)&As[row][c8]=z;
    }
    #pragma unroll
    for(int i=0;i<2;++i){
      int g=i*256+t; int row=g>>3, c8=(g&7)*8;
      short8 s=*(const short8*)&Wv[(size_t)(h*64+row)*Cn + k0 + c8];
      *(short8*)&Ws[row][c8]=s;
    }
    __syncthreads();
    #pragma unroll
    for(int ks=0;ks<64;ks+=32){
      short8 a0=*(const short8*)&As[lr   ][ks+lk];
      short8 a1=*(const short8*)&As[16+lr][ks+lk];
      short8 bf=*(const short8*)&Ws[w*16+lr][ks+lk];
      acc[0]=mfma16(a0,bf,acc[0]);
      acc[1]=mfma16(a1,bf,acc[1]);
    }
  }
  const int r0=(l>>4)*4;
  #pragma unroll
  for(int i=0;i<2;++i)
    #pragma unroll
    for(int r=0;r<4;++r){
      int qi=i*16+r0+r;
      if(qi<31)
        o2b[((size_t)b*31+qi)*Cn + h*64 + w*16 + lr]=f2b(acc[i][r]);
    }
}

// =====================================================================
extern "C" void kernel_launch(void* const* d_in, const int* in_sizes, int n_in,
                              void* d_out, int out_size, void* d_ws, size_t ws_size,
                              hipStream_t stream){
  (void)out_size; (void)ws_size;
  float* outp=(float*)d_out;                 // out (B,S,C) fp32
  float* e2  =outp + (size_t)Rn*Cn;          // energy2 (B,H,S,CTX) fp32
  if(n_in<24 || in_sizes[0]!=Rn*Cn || in_sizes[1]!=Bn*Tn*Cn ||
     in_sizes[4]!=Cn*Cn || in_sizes[9]!=961 || in_sizes[20]!=2*Cn*Cn){
    k_badorder<<<1,64,0,stream>>>(outp);
    return;
  }
  const float* queries =(const float*)d_in[0];
  const float* contexts=(const float*)d_in[1];
  const float* sa_bn_g =(const float*)d_in[2];
  const float* sa_bn_b =(const float*)d_in[3];
  const float* sa_q_w  =(const float*)d_in[4];
  const float* sa_k_w  =(const float*)d_in[5];
  const float* sa_v_w  =(const float*)d_in[6];
  const float* sa_out_w=(const float*)d_in[7];
  const float* sa_out_b=(const float*)d_in[8];
  const float* sa_pre_g=(const float*)d_in[9];
  const float* sa_pre_b=(const float*)d_in[10];
  const float* ca_ln_g =(const float*)d_in[11];
  const float* ca_ln_b =(const float*)d_in[12];
  const float* ca_q_w  =(const float*)d_in[13];
  const float* ca_k_w  =(const float*)d_in[14];
  const float* ca_v_w  =(const float*)d_in[15];
  const float* ca_out_w=(const float*)d_in[16];
  const float* ca_out_b=(const float*)d_in[17];
  const float* ff_ln1_g=(const float*)d_in[18];
  const float* ff_ln1_b=(const float*)d_in[19];
  const float* ff_w1   =(const float*)d_in[20];
  const float* ff_ln2_g=(const float*)d_in[21];
  const float* ff_ln2_b=(const float*)d_in[22];
  const float* ff_w2   =(const float*)d_in[23];

  char* ws=(char*)d_ws;
  size_t off=0;
  auto alloc=[&](size_t bytes)->char*{
    char* p=ws+off; off=(off+bytes+255)&~(size_t)255; return p;
  };
  float* ps1  =(float*)alloc(16*Cn*4);
  float* psq1 =(float*)alloc(16*Cn*4);
  float* scale1=(float*)alloc(Cn*4);
  float* shift1=(float*)alloc(Cn*4);
  // weights bf16: MUST stay contiguous & in this order (k_cvtbn writes linearly)
  u16* w_sq=(u16*)alloc((size_t)Cn*Cn*2);
  u16* w_sk=(u16*)alloc((size_t)Cn*Cn*2);
  u16* w_sv=(u16*)alloc((size_t)Cn*Cn*2);
  u16* w_so=(u16*)alloc((size_t)Cn*Cn*2);
  u16* w_cq=(u16*)alloc((size_t)Cn*Cn*2);
  u16* w_co=(u16*)alloc((size_t)Cn*Cn*2);
  u16* w_f1=(u16*)alloc((size_t)2*Cn*Cn*2);
  u16* w_f2=(u16*)alloc((size_t)2*Cn*Cn*2);
  u16* w_ck=(u16*)alloc((size_t)Cn*Cn*2);
  u16* w_cv=(u16*)alloc((size_t)Cn*Cn*2);
  u16* qb  =(u16*)alloc((size_t)Rn*Cn*2);
  u16* kb  =(u16*)alloc((size_t)Rn*Cn*2);   // qb+kb contiguous (t1 alias)
  u16* vb  =(u16*)alloc((size_t)Rn*Cn*2);
  float* e1  =(float*)alloc((size_t)BHn*961*4);
  float* ps2 =(float*)alloc(8*961*4);
  float* psq2=(float*)alloc(8*961*4);
  float* mu2 =(float*)alloc(961*4);
  float* rstd2=(float*)alloc(961*4);
  u16* o1  =(u16*)alloc((size_t)Rn*Cn*2);
  u16* xsa =(u16*)alloc((size_t)Rn*Cn*2);
  u16* qn  =(u16*)alloc((size_t)Rn*Cn*2);
  u16* q2b =(u16*)alloc((size_t)Rn*Cn*2);
  u16* qk  =(u16*)alloc((size_t)Bn*HRn*Cn*2);   // 16.25 MB
  float* psca=(float*)alloc((size_t)BHn*31*32*4); // 2 MB partial denoms
  float* st=(float*)alloc((size_t)BHn*31*4);
  u16* o2b =(u16*)alloc((size_t)Rn*Cn*2);
  u16* xca =(u16*)alloc((size_t)Rn*Cn*2);
  u16* pb  =(u16*)alloc((size_t)Bn*256*Tn*2);   // 67 MB
  u16* ctxb=(u16*)alloc((size_t)Bn*Tn*Cn*2);    // 134 MB bf16 contexts
  // aliases (non-overlapping lifetimes):
  u16* o2t = qk;     // qk dead after k_e2big
  u16* f1  = o1;     // o1 dead after SA out-proj
  u16* t1  = qb;     // spans qb+kb, dead after k_energy1
  u16* f2  = vb;     // vb dead after k_smpv

  dim3 blk256(256), blk64(64), blk512(512);
  dim3 g64(Rn/64, Cn/64);     // (31, 8)

  // ---- weight converts + bn1 partial, one launch ----
  Src10 s10;
  s10.p[0]=sa_q_w; s10.p[1]=sa_k_w; s10.p[2]=sa_v_w; s10.p[3]=sa_out_w;
  s10.p[4]=ca_q_w; s10.p[5]=ca_out_w; s10.p[6]=ff_w1; s10.p[7]=ff_w2;
  s10.p[8]=ca_k_w; s10.p[9]=ca_v_w;
  k_cvtbn<<<1568,blk256,0,stream>>>(s10, w_sq, queries, ps1, psq1);

  // ---- Self-attention ----
  k_bn1_final<<<1,512,0,stream>>>(ps1,psq1,sa_bn_g,sa_bn_b,scale1,shift1);
  k_qkv<<<dim3(31,8,3),blk256,0,stream>>>(queries,scale1,shift1,w_sq,w_sk,w_sv,qb,kb,vb);
  k_energy1<<<BHn,blk64,0,stream>>>(qb,kb,e1);
  k_bn2_partial<<<dim3(4,8),blk256,0,stream>>>(e1,ps2,psq2);
  k_bn2_final<<<1,1024,0,stream>>>(ps2,psq2,mu2,rstd2);
  k_smpv<<<BHn,blk64,0,stream>>>(e1,mu2,rstd2,sa_pre_g,sa_pre_b,vb,o1);
  k_gemm64<false,true><<<g64,blk256,0,stream>>>(o1,w_so,sa_out_b,queries,xsa,Rn,Cn,Cn);

  // ---- Cross-attention (round-19 schedule + 2-deep reg pipeline in e2big/pv2) ----
  k_ln<512,false><<<Rn/4,blk256,0,stream>>>(xsa,ca_ln_g,ca_ln_b,qn);
  k_gemm64<false,false><<<g64,blk256,0,stream>>>(qn,w_cq,nullptr,nullptr,q2b,Rn,Cn,Cn);
  k_qk<<<BHn,blk256,0,stream>>>(q2b,w_ck,qk);
  k_e2big<<<dim3(Tn/128,Bn),blk512,0,stream>>>(qk,contexts,e2,ctxb,pb,psca);
  k_castred<<<62,blk256,0,stream>>>(psca,st);
  k_pv2<<<dim3(Cn/128,2,Bn),blk512,0,stream>>>(pb,ctxb,st,o2t);
  k_o2proj<<<BHn,blk256,0,stream>>>(o2t,w_cv,o2b);
  k_gemm64<false,false><<<g64,blk256,0,stream>>>(o2b,w_co,ca_out_b,xsa,xca,Rn,Cn,Cn);

  // ---- FFN ----
  k_ln<512,true><<<Rn/4,blk256,0,stream>>>(xca,ff_ln1_g,ff_ln1_b,f1);
  k_gemm64<false,false><<<dim3(Rn/64,1024/64),blk256,0,stream>>>(f1,w_f1,nullptr,nullptr,t1,Rn,1024,Cn);
  k_ln<1024,true><<<Rn/4,blk256,0,stream>>>(t1,ff_ln2_g,ff_ln2_b,f2);
  k_gemm64<true,false><<<g64,blk256,0,stream>>>(f2,w_f2,nullptr,xca,outp,Rn,Cn,1024);
}

// Round 21
// 393.215 us; speedup vs baseline: 1.0270x; 1.0270x over previous
//
#include <hip/hip_runtime.h>
#include <hip/hip_bf16.h>
#include <cstdint>
#include <cstddef>

using u16 = unsigned short;
typedef short short8 __attribute__((ext_vector_type(8)));
typedef short short4v __attribute__((ext_vector_type(4)));
typedef float f32x4  __attribute__((ext_vector_type(4)));

#define DEV static __device__ __forceinline__

DEV float b2f(u16 u){ union{ unsigned i; float f; } v; v.i = ((unsigned)u)<<16; return v.f; }
DEV u16 f2b(float f){
  unsigned i = __builtin_bit_cast(unsigned, f);
  unsigned r = (i + 0x7FFFu + ((i>>16)&1u)) >> 16;
  return (u16)r;
}
DEV f32x4 mfma16(short8 a, short8 b, f32x4 c){
  return __builtin_amdgcn_mfma_f32_16x16x32_bf16(a, b, c, 0, 0, 0);
}
// LDS-only barrier: waits own LDS ops, then s_barrier. Global loads stay in
// flight across it (their results guarded by compiler register-dep vmcnt).
DEV void barrier_lgkm(){
  asm volatile("s_waitcnt lgkmcnt(0)" ::: "memory");
  __builtin_amdgcn_s_barrier();
}

constexpr int Bn=64, Sn=31, Tn=2048, Cn=512, Hn=8;
constexpr int Rn=Bn*Sn;           // 1984
constexpr int BHn=Bn*Hn;          // 512
constexpr int HRn=Hn*Sn;          // 248
constexpr float EPSf=1e-5f;
constexpr float INV_SCALE=0.04419417382415922f;   // 1/sqrt(512)

__global__ void k_badorder(float* out){
  if(threadIdx.x==0) out[0]=2000.f;
}

// ------- merged: 10 weight fp32->bf16 segments (blocks 0..1535) + bn1 partial (1536..1567) ----
struct Src10 { const float* p[10]; };
__global__ __launch_bounds__(256) void k_cvtbn(Src10 s, u16* __restrict__ dst,
    const float* __restrict__ q, float* __restrict__ ps, float* __restrict__ psq){
  int bid=blockIdx.x;
  if(bid<1536){
    int i = bid*256 + threadIdx.x;          // n8 index, total 393216
    int seg, j=i;
    if(j>=196608){
      if(j>=327680){ if(j>=360448){seg=9;j-=360448;} else {seg=8;j-=327680;} }
      else if(j>=262144){seg=7;j-=262144;}
      else {seg=6;j-=196608;}
    } else { seg=j>>15; j&=32767; }
    const float* src=s.p[seg];
    f32x4 a=*(const f32x4*)&src[(size_t)j*8];
    f32x4 b=*(const f32x4*)&src[(size_t)j*8+4];
    short8 o;
    #pragma unroll
    for(int qq=0;qq<4;++qq){ o[qq]=(short)f2b(a[qq]); o[4+qq]=(short)f2b(b[qq]); }
    *(short8*)&dst[(size_t)i*8]=o;
  } else {
    int bb=bid-1536;                        // 0..31
    int c = (bb&1)*256 + threadIdx.x;
    int r0 = (bb>>1)*124;
    float sum=0.f, sq=0.f;
    for(int r=r0;r<r0+124;++r){ float v=q[(size_t)r*Cn+c]; sum+=v; sq+=v*v; }
    ps [(bb>>1)*Cn+c]=sum;
    psq[(bb>>1)*Cn+c]=sq;
  }
}

__global__ __launch_bounds__(512) void k_bn1_final(const float* __restrict__ ps,
    const float* __restrict__ psq, const float* __restrict__ g,
    const float* __restrict__ b, float* __restrict__ scale, float* __restrict__ shift){
  int c = threadIdx.x;
  float s=0.f, sq=0.f;
  for(int i=0;i<16;++i){ s+=ps[i*Cn+c]; sq+=psq[i*Cn+c]; }
  float m = s/(float)Rn;
  float v = sq/(float)Rn - m*m;
  float rs = rsqrtf(v+EPSf);
  float sc = rs*g[c];
  scale[c]=sc; shift[c]=b[c]-m*sc;
}

// ---------------- fused BN + QKV projections (grid.z selects q/k/v) ------------
__global__ __launch_bounds__(256) void k_qkv(
    const float* __restrict__ q, const float* __restrict__ scale,
    const float* __restrict__ shift,
    const u16* __restrict__ W0, const u16* __restrict__ W1, const u16* __restrict__ W2,
    u16* __restrict__ o0, u16* __restrict__ o1v, u16* __restrict__ o2v)
{
  __shared__ u16 As[64][72];
  __shared__ u16 Ws[64][72];
  const int z=blockIdx.z;
  const u16* W = (z==0)?W0:((z==1)?W1:W2);
  u16* out     = (z==0)?o0:((z==1)?o1v:o2v);
  const int t=threadIdx.x, w=t>>6, l=t&63;
  const int m0=blockIdx.x*64, n0=blockIdx.y*64;
  const int lr=l&15, lk=(l>>4)*8;
  f32x4 zero={0.f,0.f,0.f,0.f};
  f32x4 acc[4];
  #pragma unroll
  for(int i=0;i<4;++i) acc[i]=zero;
  const int row0=t>>3, c8=(t&7)*8;
  for(int k0=0;k0<Cn;k0+=64){
    f32x4 sc0=*(const f32x4*)&scale[k0+c8], sc1=*(const f32x4*)&scale[k0+c8+4];
    f32x4 sh0=*(const f32x4*)&shift[k0+c8], sh1=*(const f32x4*)&shift[k0+c8+4];
    f32x4 x00=*(const f32x4*)&q[(size_t)(m0+row0   )*Cn+k0+c8];
    f32x4 x01=*(const f32x4*)&q[(size_t)(m0+row0   )*Cn+k0+c8+4];
    f32x4 x10=*(const f32x4*)&q[(size_t)(m0+32+row0)*Cn+k0+c8];
    f32x4 x11=*(const f32x4*)&q[(size_t)(m0+32+row0)*Cn+k0+c8+4];
    short8 a0,a1;
    #pragma unroll
    for(int j=0;j<4;++j){
      a0[j]  =(short)f2b(fmaf(x00[j],sc0[j],sh0[j]));
      a0[4+j]=(short)f2b(fmaf(x01[j],sc1[j],sh1[j]));
      a1[j]  =(short)f2b(fmaf(x10[j],sc0[j],sh0[j]));
      a1[4+j]=(short)f2b(fmaf(x11[j],sc1[j],sh1[j]));
    }
    short8 w0=*(const short8*)&W[(size_t)(n0+row0   )*Cn + k0 + c8];
    short8 w1=*(const short8*)&W[(size_t)(n0+32+row0)*Cn + k0 + c8];
    __syncthreads();
    *(short8*)&As[row0   ][c8]=a0;
    *(short8*)&As[32+row0][c8]=a1;
    *(short8*)&Ws[row0   ][c8]=w0;
    *(short8*)&Ws[32+row0][c8]=w1;
    __syncthreads();
    #pragma unroll
    for(int ks=0;ks<64;ks+=32){
      short8 af=*(const short8*)&As[w*16+lr][ks+lk];
      #pragma unroll
      for(int nf=0;nf<4;++nf){
        short8 bf=*(const short8*)&Ws[nf*16+lr][ks+lk];
        acc[nf]=mfma16(af,bf,acc[nf]);
      }
    }
  }
  const int r0=w*16+(l>>4)*4;
  #pragma unroll
  for(int nf=0;nf<4;++nf){
    const int n=n0+nf*16+lr;
    #pragma unroll
    for(int r=0;r<4;++r){
      const int m=m0+r0+r;
      out[(size_t)m*Cn+n]=f2b(acc[nf][r]);
    }
  }
}

// ---------------- generic 64x64-tile GEMM: out = A * W^T (+bias)(+res) ----------------
template<bool F32OUT, bool RES32>
__global__ __launch_bounds__(256) void k_gemm64(
    const u16* __restrict__ A, const u16* __restrict__ W,
    const float* __restrict__ bias, const void* __restrict__ res,
    void* __restrict__ outv, int M, int N, int K)
{
  __shared__ u16 As[64][72];
  __shared__ u16 Ws[64][72];
  const int t=threadIdx.x, w=t>>6, l=t&63;
  const int m0=blockIdx.x*64, n0=blockIdx.y*64;
  const int lr=l&15, lk=(l>>4)*8;
  f32x4 zero={0.f,0.f,0.f,0.f};
  f32x4 acc[4];
  #pragma unroll
  for(int i=0;i<4;++i) acc[i]=zero;
  const int row0=t>>3, c8=(t&7)*8;
  for(int k0=0;k0<K;k0+=64){
    short8 a0=*(const short8*)&A[(size_t)(m0+row0   )*K + k0 + c8];
    short8 a1=*(const short8*)&A[(size_t)(m0+32+row0)*K + k0 + c8];
    short8 w0=*(const short8*)&W[(size_t)(n0+row0   )*K + k0 + c8];
    short8 w1=*(const short8*)&W[(size_t)(n0+32+row0)*K + k0 + c8];
    __syncthreads();
    *(short8*)&As[row0   ][c8]=a0;
    *(short8*)&As[32+row0][c8]=a1;
    *(short8*)&Ws[row0   ][c8]=w0;
    *(short8*)&Ws[32+row0][c8]=w1;
    __syncthreads();
    #pragma unroll
    for(int ks=0;ks<64;ks+=32){
      short8 af=*(const short8*)&As[w*16+lr][ks+lk];
      #pragma unroll
      for(int nf=0;nf<4;++nf){
        short8 bf=*(const short8*)&Ws[nf*16+lr][ks+lk];
        acc[nf]=mfma16(af,bf,acc[nf]);
      }
    }
  }
  const int r0=w*16+(l>>4)*4;
  #pragma unroll
  for(int nf=0;nf<4;++nf){
    const int n=n0+nf*16+lr;
    float bv = bias? bias[n] : 0.f;
    #pragma unroll
    for(int r=0;r<4;++r){
      const int m=m0+r0+r;
      float vv=acc[nf][r]+bv;
      if(res){
        if(RES32) vv += ((const float*)res)[(size_t)m*N+n];
        else      vv += b2f(((const u16*)res)[(size_t)m*N+n]);
      }
      if(F32OUT) ((float*)outv)[(size_t)m*N+n]=vv;
      else       ((u16*)outv)[(size_t)m*N+n]=f2b(vv);
    }
  }
}

// ---------------- SA energy: per (b,h) 31x31 = q[31x64] * k[31x64]^T ----------------
__global__ __launch_bounds__(64) void k_energy1(const u16* __restrict__ q,
    const u16* __restrict__ k, float* __restrict__ e1){
  __shared__ u16 qs[32][72];
  __shared__ u16 ks_[32][72];
  const int bh=blockIdx.x, b=bh>>3, h=bh&7;
  const int t=threadIdx.x, l=t;
  #pragma unroll
  for(int i=0;i<4;++i){
    int flat=i*64+t; int row=flat>>3, c8=(flat&7)*8;
    short8 zq={0,0,0,0,0,0,0,0}, zk={0,0,0,0,0,0,0,0};
    if(row<31){
      zq=*(const short8*)&q[(size_t)(b*31+row)*Cn + h*64 + c8];
      zk=*(const short8*)&k[(size_t)(b*31+row)*Cn + h*64 + c8];
    }
    *(short8*)&qs [row][c8]=zq;
    *(short8*)&ks_[row][c8]=zk;
  }
  __syncthreads();
  const int lr=l&15, lk=(l>>4)*8;
  f32x4 zero={0.f,0.f,0.f,0.f};
  f32x4 acc[2][2];
  acc[0][0]=zero; acc[0][1]=zero; acc[1][0]=zero; acc[1][1]=zero;
  #pragma unroll
  for(int ks=0;ks<64;ks+=32){
    short8 a0=*(const short8*)&qs [lr   ][ks+lk];
    short8 a1=*(const short8*)&qs [16+lr][ks+lk];
    short8 b0=*(const short8*)&ks_[lr   ][ks+lk];
    short8 b1=*(const short8*)&ks_[16+lr][ks+lk];
    acc[0][0]=mfma16(a0,b0,acc[0][0]);
    acc[0][1]=mfma16(a0,b1,acc[0][1]);
    acc[1][0]=mfma16(a1,b0,acc[1][0]);
    acc[1][1]=mfma16(a1,b1,acc[1][1]);
  }
  const int r0=(l>>4)*4;
  #pragma unroll
  for(int i=0;i<2;++i)
    #pragma unroll
    for(int j=0;j<2;++j)
      #pragma unroll
      for(int r=0;r<4;++r){
        int qi=i*16+r0+r, ki=j*16+lr;
        if(qi<31 && ki<31) e1[(size_t)bh*961 + qi*31 + ki]=acc[i][j][r];
      }
}

// ---------------- BN over (B,H) on energy positions p=0..960 ----------------
__global__ __launch_bounds__(256) void k_bn2_partial(const float* __restrict__ e1,
    float* __restrict__ ps, float* __restrict__ psq){
  int p=blockIdx.x*256+threadIdx.x;
  if(p>=961) return;
  int r0=blockIdx.y*64;
  float s=0.f, sq=0.f;
  for(int r=r0;r<r0+64;++r){ float v=e1[(size_t)r*961+p]; s+=v; sq+=v*v; }
  ps [blockIdx.y*961+p]=s;
  psq[blockIdx.y*961+p]=sq;
}
__global__ __launch_bounds__(1024) void k_bn2_final(const float* __restrict__ ps,
    const float* __restrict__ psq, float* __restrict__ mu2, float* __restrict__ rstd2){
  int p=threadIdx.x; if(p>=961) return;
  float s=0.f, sq=0.f;
  for(int i=0;i<8;++i){ s+=ps[i*961+p]; sq+=psq[i*961+p]; }
  float m=s/512.f, v=sq/512.f-m*m;
  mu2[p]=m; rstd2[p]=rsqrtf(v+EPSf);
}

// ---------------- fused SA softmax (BN2-applied) + PV, one block per (b,h) --------
__global__ __launch_bounds__(64) void k_smpv(const float* __restrict__ e1,
    const float* __restrict__ mu2, const float* __restrict__ rstd2,
    const float* __restrict__ g2, const float* __restrict__ bb2,
    const u16* __restrict__ v, u16* __restrict__ o1){
  __shared__ u16 at[32][40];   // softmax probs, bf16
  __shared__ u16 vs[64][40];   // transposed V: vs[dh][kv]
  const int bh=blockIdx.x, b=bh>>3, h=bh&7;
  const int l=threadIdx.x;
  for(int kv=0;kv<31;++kv) vs[l][kv]=v[(size_t)(b*31+kv)*Cn + h*64 + l];
  vs[l][31]=0;
  if(l<31){
    const float* er=e1+(size_t)bh*961 + l*31;
    float lg[31]; float mx=-1e30f;
    #pragma unroll
    for(int kk=0;kk<31;++kk){
      int p=l*31+kk;
      float en=(er[kk]-mu2[p])*rstd2[p]*g2[p]+bb2[p];
      lg[kk]=en*INV_SCALE;
      mx=fmaxf(mx,lg[kk]);
    }
    float s=0.f;
    #pragma unroll
    for(int kk=0;kk<31;++kk){ lg[kk]=__expf(lg[kk]-mx); s+=lg[kk]; }
    float inv=1.f/s;
    #pragma unroll
    for(int kk=0;kk<31;++kk) at[l][kk]=f2b(lg[kk]*inv);
    at[l][31]=0;
  } else if(l==31){
    #pragma unroll
    for(int kk=0;kk<32;++kk) at[31][kk]=0;
  }
  __syncthreads();
  const int lr=l&15, lk=(l>>4)*8;
  f32x4 zero={0.f,0.f,0.f,0.f};
  f32x4 acc[2][4];
  #pragma unroll
  for(int i=0;i<2;++i)
    #pragma unroll
    for(int nf=0;nf<4;++nf) acc[i][nf]=zero;
  short8 a0=*(const short8*)&at[lr   ][lk];
  short8 a1=*(const short8*)&at[16+lr][lk];
  #pragma unroll
  for(int nf=0;nf<4;++nf){
    short8 bf=*(const short8*)&vs[nf*16+lr][lk];
    acc[0][nf]=mfma16(a0,bf,acc[0][nf]);
    acc[1][nf]=mfma16(a1,bf,acc[1][nf]);
  }
  const int r0=(l>>4)*4;
  #pragma unroll
  for(int i=0;i<2;++i)
    #pragma unroll
    for(int nf=0;nf<4;++nf)
      #pragma unroll
      for(int r=0;r<4;++r){
        int qi=i*16+r0+r;
        if(qi<31){
          int dh=nf*16+lr;
          o1[(size_t)(b*31+qi)*Cn + h*64 + dh]=f2b(acc[i][nf][r]);
        }
      }
}

// ---------------- row LayerNorm (optionally + SiLU), wave per row ----------------
template<int Wd, bool SILU>
__global__ __launch_bounds__(256) void k_ln(const u16* __restrict__ x,
    const float* __restrict__ g, const float* __restrict__ b, u16* __restrict__ out){
  const int w=threadIdx.x>>6, l=threadIdx.x&63;
  const int row=blockIdx.x*4+w;
  constexpr int NC=Wd/512;
  float v[NC*8];
  #pragma unroll
  for(int i=0;i<NC;++i){
    short8 s=*(const short8*)&x[(size_t)row*Wd + i*512 + l*8];
    #pragma unroll
    for(int j=0;j<8;++j) v[i*8+j]=b2f((u16)s[j]);
  }
  float s1=0.f, s2=0.f;
  #pragma unroll
  for(int e=0;e<NC*8;++e){ s1+=v[e]; s2+=v[e]*v[e]; }
  #pragma unroll
  for(int off=1;off<64;off<<=1){ s1+=__shfl_xor(s1,off,64); s2+=__shfl_xor(s2,off,64); }
  float m=s1/(float)Wd, var=s2/(float)Wd-m*m, rs=rsqrtf(var+EPSf);
  #pragma unroll
  for(int i=0;i<NC;++i){
    short8 o;
    #pragma unroll
    for(int j=0;j<8;++j){
      int c=i*512+l*8+j;
      float y=(v[i*8+j]-m)*rs*g[c]+b[c];
      if(SILU) y=y/(1.f+__expf(-y));
      o[j]=(short)f2b(y);
    }
    *(short8*)&out[(size_t)row*Wd + i*512 + l*8]=o;
  }
}

// ---------------- CA step 1: qk = q2_h (31x64) . Wk_h (64x512), Wk bf16 ----
__global__ __launch_bounds__(256) void k_qk(const u16* __restrict__ q2,
    const u16* __restrict__ Wk, u16* __restrict__ qk){
  __shared__ u16 qs[32][72];
  __shared__ u16 bt[128][72];    // bt[c][d] = Wk[h*64+d][nc+c]
  const int bh=blockIdx.x, b=bh>>3, h=bh&7;
  const int t=threadIdx.x, w=t>>6, l=t&63;
  {
    int row=t>>3, c8=(t&7)*8;
    short8 z={0,0,0,0,0,0,0,0};
    if(row<31) z=*(const short8*)&q2[(size_t)(b*31+row)*Cn + h*64 + c8];
    *(short8*)&qs[row][c8]=z;
  }
  const int lr=l&15, lk=(l>>4)*8;
  const int r0=(l>>4)*4;
  for(int nc=0;nc<512;nc+=128){
    __syncthreads();
    #pragma unroll
    for(int i=0;i<4;++i){
      int g=i*256+t;             // 0..1023
      int d=g>>4, c8=(g&15)*8;
      short8 s=*(const short8*)&Wk[(size_t)(h*64+d)*Cn + nc + c8];
      #pragma unroll
      for(int jj=0;jj<8;++jj) bt[c8+jj][d]=(u16)s[jj];
    }
    __syncthreads();
    f32x4 zero={0.f,0.f,0.f,0.f};
    f32x4 acc[2][2];
    acc[0][0]=zero; acc[0][1]=zero; acc[1][0]=zero; acc[1][1]=zero;
    #pragma unroll
    for(int ks=0;ks<64;ks+=32){
      short8 a0=*(const short8*)&qs[lr   ][ks+lk];
      short8 a1=*(const short8*)&qs[16+lr][ks+lk];
      #pragma unroll
      for(int nf=0;nf<2;++nf){
        short8 bf=*(const short8*)&bt[w*32+nf*16+lr][ks+lk];
        acc[0][nf]=mfma16(a0,bf,acc[0][nf]);
        acc[1][nf]=mfma16(a1,bf,acc[1][nf]);
      }
    }
    #pragma unroll
    for(int i=0;i<2;++i)
      #pragma unroll
      for(int nf=0;nf<2;++nf)
        #pragma unroll
        for(int r=0;r<4;++r){
          int qi=i*16+r0+r;
          if(qi<31)
            qk[((size_t)b*HRn + h*31 + qi)*Cn + nc + w*32 + nf*16 + lr]=f2b(acc[i][nf][r]);
        }
  }
}

// ---------------- CA step 2: e2(fp32) = qk . ctx^T ; exports ctxb bf16,
//                  P=exp(e2*s) bf16 into pb, partial denoms into psca.
//                  XCD-swizzled + LDS-only barriers (loads span barriers). ----
__global__ __launch_bounds__(512) void k_e2big(const u16* __restrict__ qk,
    const float* __restrict__ ctx, float* __restrict__ e2, u16* __restrict__ ctxb,
    u16* __restrict__ pb, float* __restrict__ psca){
  __shared__ u16 As[256][72];
  __shared__ u16 Bs[128][72];
  // XCD swizzle (T1): nwg=1024, cpx=128; swz=(bid%8)*128+bid/8 (bijective)
  const int bid = blockIdx.x + 16*blockIdx.y;
  const int swz = (bid&7)*128 + (bid>>3);
  const int b   = swz>>4;
  const int tb  = (swz&15)*128;
  const int t=threadIdx.x, w=t>>6, l=t&63;
  const int lr=l&15, lk=(l>>4)*8;
  const int wr=(w>>1)*64, wc=(w&1)*64;
  f32x4 zero={0.f,0.f,0.f,0.f};
  f32x4 acc[4][4];
  #pragma unroll
  for(int i=0;i<4;++i)
    #pragma unroll
    for(int j=0;j<4;++j) acc[i][j]=zero;

  const int arow[4]={ (0*512+t)>>3, (1*512+t)>>3, (2*512+t)>>3, (3*512+t)>>3 };
  const int ac8=(t&7)*8;
  const int brow=t>>4, bc4=(t&15)*4;     // 512 threads -> rows 0..31 per i-chunk
  short8 areg[4];
  f32x4  breg[4];
  auto loadK=[&](int k0){
    #pragma unroll
    for(int i=0;i<4;++i){
      short8 z={0,0,0,0,0,0,0,0};
      if(arow[i]<HRn) z=*(const short8*)&qk[((size_t)b*HRn+arow[i])*Cn + k0 + ac8];
      areg[i]=z;
    }
    #pragma unroll
    for(int i=0;i<4;++i)
      breg[i]=*(const f32x4*)&ctx[((size_t)b*Tn + tb + i*32+brow)*Cn + k0 + bc4];
  };
  loadK(0);
  for(int k0=0;k0<512;k0+=64){
    barrier_lgkm();
    #pragma unroll
    for(int i=0;i<4;++i) *(short8*)&As[arow[i]][ac8]=areg[i];
    #pragma unroll
    for(int i=0;i<4;++i){
      short4v o;
      #pragma unroll
      for(int jj=0;jj<4;++jj) o[jj]=(short)f2b(breg[i][jj]);
      *(short4v*)&Bs[i*32+brow][bc4]=o;
      *(short4v*)&ctxb[((size_t)b*Tn + tb + i*32+brow)*Cn + k0 + bc4]=o;
    }
    barrier_lgkm();
    if(k0+64<512) loadK(k0+64);
    #pragma unroll
    for(int ks=0;ks<64;ks+=32){
      short8 af[4], bf[4];
      #pragma unroll
      for(int i=0;i<4;++i){
        af[i]=*(const short8*)&As[wr+i*16+lr][ks+lk];
        bf[i]=*(const short8*)&Bs[wc+i*16+lr][ks+lk];
      }
      #pragma unroll
      for(int i=0;i<4;++i)
        #pragma unroll
        for(int j=0;j<4;++j)
          acc[i][j]=mfma16(af[i],bf[j],acc[i][j]);
    }
  }
  const int r0=(l>>4)*4;
  #pragma unroll
  for(int i=0;i<4;++i)
    #pragma unroll
    for(int r=0;r<4;++r){
      int rm=wr+i*16+r0+r;
      float psum=0.f;
      #pragma unroll
      for(int j=0;j<4;++j){
        float vv=acc[i][j][r];
        if(rm<HRn){
          size_t col = tb + wc + j*16 + lr;
          e2[((size_t)b*HRn+rm)*Tn + col]=vv;
          float p=__expf(vv*INV_SCALE);
          pb[((size_t)b*256+rm)*Tn + col]=f2b(p);
          psum+=p;
        }
      }
      // reduce over the 16 lanes (lr) that share this row
      psum+=__shfl_xor(psum,1,64);
      psum+=__shfl_xor(psum,2,64);
      psum+=__shfl_xor(psum,4,64);
      psum+=__shfl_xor(psum,8,64);
      if(rm<HRn && lr==0)
        psca[((size_t)b*HRn+rm)*32 + (tb>>7)*2 + (wc>>6)]=psum;
    }
}

// ---------------- reduce 32 partials per row -> denom st[row] ----------------
__global__ __launch_bounds__(256) void k_castred(const float* __restrict__ psca,
    float* __restrict__ st){
  int i=blockIdx.x*256+threadIdx.x;   // 0..15871
  if(i>=BHn*31) return;
  float s=0.f;
  #pragma unroll
  for(int j=0;j<32;++j) s+=psca[(size_t)i*32+j];
  st[i]=s;
}

// ---------------- CA step 3: o2t = P . ctxb, XCD-swizzled + LDS-only barriers ----
__global__ __launch_bounds__(512) void k_pv2(const u16* __restrict__ pb,
    const u16* __restrict__ ctxb, const float* __restrict__ st,
    u16* __restrict__ o2t){
  __shared__ u16 As[128][72];
  __shared__ u16 Bs[128][76];
  // XCD swizzle (T1): nwg=512, cpx=64; swz=(bid%8)*64+bid/8 (bijective)
  const int bid = blockIdx.x + 4*(blockIdx.y + 2*blockIdx.z);
  const int swz = (bid&7)*64 + (bid>>3);
  const int b   = swz>>3;
  const int m0  = ((swz>>2)&1)*128;
  const int n0  = (swz&3)*128;
  const int t=threadIdx.x, w=t>>6, l=t&63;
  const int lr=l&15, lk=(l>>4)*8;
  const int wm=(w>>2)*64, wn=(w&3)*32;
  f32x4 zero={0.f,0.f,0.f,0.f};
  f32x4 acc[4][2];
  #pragma unroll
  for(int i=0;i<4;++i){ acc[i][0]=zero; acc[i][1]=zero; }
  const int arow=t>>3, ac8=(t&7)*8;     // A staging (2 iters)
  const int bc=t&127, bq=(t>>7)*4;      // B staging: column bc, quads bq..bq+3
  short8 areg[2];
  u16 breg[16];
  auto loadK=[&](int kb){
    #pragma unroll
    for(int i=0;i<2;++i)
      areg[i]=*(const short8*)&pb[((size_t)b*256 + m0 + arow+i*64)*Tn + kb + ac8];
    #pragma unroll
    for(int i=0;i<4;++i){
      int kt0=(bq+i)*4;
      #pragma unroll
      for(int jj=0;jj<4;++jj)
        breg[i*4+jj]=ctxb[((size_t)b*Tn + kb + kt0 + jj)*Cn + n0 + bc];
    }
  };
  loadK(0);
  for(int kb=0;kb<Tn;kb+=64){
    barrier_lgkm();
    #pragma unroll
    for(int i=0;i<2;++i) *(short8*)&As[arow+i*64][ac8]=areg[i];
    #pragma unroll
    for(int i=0;i<4;++i){
      short4v o;
      #pragma unroll
      for(int jj=0;jj<4;++jj) o[jj]=(short)breg[i*4+jj];
      *(short4v*)&Bs[bc][(bq+i)*4]=o;
    }
    barrier_lgkm();
    if(kb+64<Tn) loadK(kb+64);
    #pragma unroll
    for(int ks=0;ks<64;ks+=32){
      short8 af[4], bf[2];
      #pragma unroll
      for(int i=0;i<4;++i)
        af[i]=*(const short8*)&As[wm+i*16+lr][ks+lk];
      #pragma unroll
      for(int j=0;j<2;++j){
        const u16* p=&Bs[wn+j*16+lr][ks+lk];
        short4v lo=*(const short4v*)p;
        short4v hi=*(const short4v*)(p+4);
        short8 bb;
        #pragma unroll
        for(int jj=0;jj<4;++jj){ bb[jj]=lo[jj]; bb[4+jj]=hi[jj]; }
        bf[j]=bb;
      }
      #pragma unroll
      for(int i=0;i<4;++i)
        #pragma unroll
        for(int j=0;j<2;++j)
          acc[i][j]=mfma16(af[i],bf[j],acc[i][j]);
    }
  }
  const int r0=(l>>4)*4;
  #pragma unroll
  for(int i=0;i<4;++i)
    #pragma unroll
    for(int j=0;j<2;++j)
      #pragma unroll
      for(int r=0;r<4;++r){
        int rm=m0+wm+i*16+r0+r;
        if(rm<HRn){
          float inv=1.f/st[(size_t)b*HRn+rm];
          o2t[((size_t)b*HRn+rm)*Cn + n0+wn+j*16+lr]=f2b(acc[i][j][r]*inv);
        }
      }
}

// ---------------- CA step 4: o2b = o2t_h (31x512) . Wv_h^T (64x512), Wv bf16 ------
__global__ __launch_bounds__(256) void k_o2proj(const u16* __restrict__ o2t,
    const u16* __restrict__ Wv, u16* __restrict__ o2b){
  __shared__ u16 As[32][72];
  __shared__ u16 Ws[64][72];
  const int bh=blockIdx.x, b=bh>>3, h=bh&7;
  const int t=threadIdx.x, w=t>>6, l=t&63;
  const int lr=l&15, lk=(l>>4)*8;
  f32x4 zero={0.f,0.f,0.f,0.f};
  f32x4 acc[2]; acc[0]=zero; acc[1]=zero;
  for(int k0=0;k0<512;k0+=64){
    __syncthreads();
    {
      int row=t>>3, c8=(t&7)*8;
      short8 z={0,0,0,0,0,0,0,0};
      if(row<31) z=*(const short8*)&o2t[((size_t)b*HRn + h*31 + row)*Cn + k0 + c8];
      *(short8*)&As[row][c8]=z;
    }
    #pragma unroll
    for(int i=0;i<2;++i){
      int g=i*256+t; int row=g>>3, c8=(g&7)*8;
      short8 s=*(const short8*)&Wv[(size_t)(h*64+row)*Cn + k0 + c8];
      *(short8*)&Ws[row][c8]=s;
    }
    __syncthreads();
    #pragma unroll
    for(int ks=0;ks<64;ks+=32){
      short8 a0=*(const short8*)&As[lr   ][ks+lk];
      short8 a1=*(const short8*)&As[16+lr][ks+lk];
      short8 bf=*(const short8*)&Ws[w*16+lr][ks+lk];
      acc[0]=mfma16(a0,bf,acc[0]);
      acc[1]=mfma16(a1,bf,acc[1]);
    }
  }
  const int r0=(l>>4)*4;
  #pragma unroll
  for(int i=0;i<2;++i)
    #pragma unroll
    for(int r=0;r<4;++r){
      int qi=i*16+r0+r;
      if(qi<31)
        o2b[((size_t)b*31+qi)*Cn + h*64 + w*16 + lr]=f2b(acc[i][r]);
    }
}

// =====================================================================
extern "C" void kernel_launch(void* const* d_in, const int* in_sizes, int n_in,
                              void* d_out, int out_size, void* d_ws, size_t ws_size,
                              hipStream_t stream){
  (void)out_size; (void)ws_size;
  float* outp=(float*)d_out;                 // out (B,S,C) fp32
  float* e2  =outp + (size_t)Rn*Cn;          // energy2 (B,H,S,CTX) fp32
  if(n_in<24 || in_sizes[0]!=Rn*Cn || in_sizes[1]!=Bn*Tn*Cn ||
     in_sizes[4]!=Cn*Cn || in_sizes[9]!=961 || in_sizes[20]!=2*Cn*Cn){
    k_badorder<<<1,64,0,stream>>>(outp);
    return;
  }
  const float* queries =(const float*)d_in[0];
  const float* contexts=(const float*)d_in[1];
  const float* sa_bn_g =(const float*)d_in[2];
  const float* sa_bn_b =(const float*)d_in[3];
  const float* sa_q_w  =(const float*)d_in[4];
  const float* sa_k_w  =(const float*)d_in[5];
  const float* sa_v_w  =(const float*)d_in[6];
  const float* sa_out_w=(const float*)d_in[7];
  const float* sa_out_b=(const float*)d_in[8];
  const float* sa_pre_g=(const float*)d_in[9];
  const float* sa_pre_b=(const float*)d_in[10];
  const float* ca_ln_g =(const float*)d_in[11];
  const float* ca_ln_b =(const float*)d_in[12];
  const float* ca_q_w  =(const float*)d_in[13];
  const float* ca_k_w  =(const float*)d_in[14];
  const float* ca_v_w  =(const float*)d_in[15];
  const float* ca_out_w=(const float*)d_in[16];
  const float* ca_out_b=(const float*)d_in[17];
  const float* ff_ln1_g=(const float*)d_in[18];
  const float* ff_ln1_b=(const float*)d_in[19];
  const float* ff_w1   =(const float*)d_in[20];
  const float* ff_ln2_g=(const float*)d_in[21];
  const float* ff_ln2_b=(const float*)d_in[22];
  const float* ff_w2   =(const float*)d_in[23];

  char* ws=(char*)d_ws;
  size_t off=0;
  auto alloc=[&](size_t bytes)->char*{
    char* p=ws+off; off=(off+bytes+255)&~(size_t)255; return p;
  };
  float* ps1  =(float*)alloc(16*Cn*4);
  float* psq1 =(float*)alloc(16*Cn*4);
  float* scale1=(float*)alloc(Cn*4);
  float* shift1=(float*)alloc(Cn*4);
  // weights bf16: MUST stay contiguous & in this order (k_cvtbn writes linearly)
  u16* w_sq=(u16*)alloc((size_t)Cn*Cn*2);
  u16* w_sk=(u16*)alloc((size_t)Cn*Cn*2);
  u16* w_sv=(u16*)alloc((size_t)Cn*Cn*2);
  u16* w_so=(u16*)alloc((size_t)Cn*Cn*2);
  u16* w_cq=(u16*)alloc((size_t)Cn*Cn*2);
  u16* w_co=(u16*)alloc((size_t)Cn*Cn*2);
  u16* w_f1=(u16*)alloc((size_t)2*Cn*Cn*2);
  u16* w_f2=(u16*)alloc((size_t)2*Cn*Cn*2);
  u16* w_ck=(u16*)alloc((size_t)Cn*Cn*2);
  u16* w_cv=(u16*)alloc((size_t)Cn*Cn*2);
  u16* qb  =(u16*)alloc((size_t)Rn*Cn*2);
  u16* kb  =(u16*)alloc((size_t)Rn*Cn*2);   // qb+kb contiguous (t1 alias)
  u16* vb  =(u16*)alloc((size_t)Rn*Cn*2);
  float* e1  =(float*)alloc((size_t)BHn*961*4);
  float* ps2 =(float*)alloc(8*961*4);
  float* psq2=(float*)alloc(8*961*4);
  float* mu2 =(float*)alloc(961*4);
  float* rstd2=(float*)alloc(961*4);
  u16* o1  =(u16*)alloc((size_t)Rn*Cn*2);
  u16* xsa =(u16*)alloc((size_t)Rn*Cn*2);
  u16* qn  =(u16*)alloc((size_t)Rn*Cn*2);
  u16* q2b =(u16*)alloc((size_t)Rn*Cn*2);
  u16* qk  =(u16*)alloc((size_t)Bn*HRn*Cn*2);   // 16.25 MB
  float* psca=(float*)alloc((size_t)BHn*31*32*4); // 2 MB partial denoms
  float* st=(float*)alloc((size_t)BHn*31*4);
  u16* o2b =(u16*)alloc((size_t)Rn*Cn*2);
  u16* xca =(u16*)alloc((size_t)Rn*Cn*2);
  u16* pb  =(u16*)alloc((size_t)Bn*256*Tn*2);   // 67 MB
  u16* ctxb=(u16*)alloc((size_t)Bn*Tn*Cn*2);    // 134 MB bf16 contexts
  // aliases (non-overlapping lifetimes):
  u16* o2t = qk;     // qk dead after k_e2big
  u16* f1  = o1;     // o1 dead after SA out-proj
  u16* t1  = qb;     // spans qb+kb, dead after k_energy1
  u16* f2  = vb;     // vb dead after k_smpv

  dim3 blk256(256), blk64(64), blk512(512);
  dim3 g64(Rn/64, Cn/64);     // (31, 8)

  // ---- weight converts + bn1 partial, one launch ----
  Src10 s10;
  s10.p[0]=sa_q_w; s10.p[1]=sa_k_w; s10.p[2]=sa_v_w; s10.p[3]=sa_out_w;
  s10.p[4]=ca_q_w; s10.p[5]=ca_out_w; s10.p[6]=ff_w1; s10.p[7]=ff_w2;
  s10.p[8]=ca_k_w; s10.p[9]=ca_v_w;
  k_cvtbn<<<1568,blk256,0,stream>>>(s10, w_sq, queries, ps1, psq1);

  // ---- Self-attention ----
  k_bn1_final<<<1,512,0,stream>>>(ps1,psq1,sa_bn_g,sa_bn_b,scale1,shift1);
  k_qkv<<<dim3(31,8,3),blk256,0,stream>>>(queries,scale1,shift1,w_sq,w_sk,w_sv,qb,kb,vb);
  k_energy1<<<BHn,blk64,0,stream>>>(qb,kb,e1);
  k_bn2_partial<<<dim3(4,8),blk256,0,stream>>>(e1,ps2,psq2);
  k_bn2_final<<<1,1024,0,stream>>>(ps2,psq2,mu2,rstd2);
  k_smpv<<<BHn,blk64,0,stream>>>(e1,mu2,rstd2,sa_pre_g,sa_pre_b,vb,o1);
  k_gemm64<false,true><<<g64,blk256,0,stream>>>(o1,w_so,sa_out_b,queries,xsa,Rn,Cn,Cn);

  // ---- Cross-attention (round-19 best schedule) ----
  k_ln<512,false><<<Rn/4,blk256,0,stream>>>(xsa,ca_ln_g,ca_ln_b,qn);
  k_gemm64<false,false><<<g64,blk256,0,stream>>>(qn,w_cq,nullptr,nullptr,q2b,Rn,Cn,Cn);
  k_qk<<<BHn,blk256,0,stream>>>(q2b,w_ck,qk);
  k_e2big<<<dim3(Tn/128,Bn),blk512,0,stream>>>(qk,contexts,e2,ctxb,pb,psca);
  k_castred<<<62,blk256,0,stream>>>(psca,st);
  k_pv2<<<dim3(Cn/128,2,Bn),blk512,0,stream>>>(pb,ctxb,st,o2t);
  k_o2proj<<<BHn,blk256,0,stream>>>(o2t,w_cv,o2b);
  k_gemm64<false,false><<<g64,blk256,0,stream>>>(o2b,w_co,ca_out_b,xsa,xca,Rn,Cn,Cn);

  // ---- FFN ----
  k_ln<512,true><<<Rn/4,blk256,0,stream>>>(xca,ff_ln1_g,ff_ln1_b,f1);
  k_gemm64<false,false><<<dim3(Rn/64,1024/64),blk256,0,stream>>>(f1,w_f1,nullptr,nullptr,t1,Rn,1024,Cn);
  k_ln<1024,true><<<Rn/4,blk256,0,stream>>>(t1,ff_ln2_g,ff_ln2_b,f2);
  k_gemm64<true,false><<<g64,blk256,0,stream>>>(f2,w_f2,nullptr,xca,outp,Rn,Cn,1024);
}

// Round 22
// 392.116 us; speedup vs baseline: 1.0299x; 1.0028x over previous
//
#include <hip/hip_runtime.h>
#include <hip/hip_bf16.h>
#include <cstdint>
#include <cstddef>

using u16 = unsigned short;
typedef short short8 __attribute__((ext_vector_type(8)));
typedef short short4v __attribute__((ext_vector_type(4)));
typedef float f32x4  __attribute__((ext_vector_type(4)));

#define DEV static __device__ __forceinline__

DEV float b2f(u16 u){ union{ unsigned i; float f; } v; v.i = ((unsigned)u)<<16; return v.f; }
DEV u16 f2b(float f){
  unsigned i = __builtin_bit_cast(unsigned, f);
  unsigned r = (i + 0x7FFFu + ((i>>16)&1u)) >> 16;
  return (u16)r;
}
DEV f32x4 mfma16(short8 a, short8 b, f32x4 c){
  return __builtin_amdgcn_mfma_f32_16x16x32_bf16(a, b, c, 0, 0, 0);
}
// LDS-only barrier: waits own LDS ops, then s_barrier. Global loads stay in
// flight across it (their results guarded by compiler register-dep vmcnt).
DEV void barrier_lgkm(){
  asm volatile("s_waitcnt lgkmcnt(0)" ::: "memory");
  __builtin_amdgcn_s_barrier();
}

constexpr int Bn=64, Sn=31, Tn=2048, Cn=512, Hn=8;
constexpr int Rn=Bn*Sn;           // 1984
constexpr int BHn=Bn*Hn;          // 512
constexpr int HRn=Hn*Sn;          // 248
constexpr float EPSf=1e-5f;
constexpr float INV_SCALE=0.04419417382415922f;   // 1/sqrt(512)

__global__ void k_badorder(float* out){
  if(threadIdx.x==0) out[0]=2000.f;
}

// ------- merged: 10 weight fp32->bf16 segments (blocks 0..1535) + bn1 partial (1536..1567) ----
struct Src10 { const float* p[10]; };
__global__ __launch_bounds__(256) void k_cvtbn(Src10 s, u16* __restrict__ dst,
    const float* __restrict__ q, float* __restrict__ ps, float* __restrict__ psq){
  int bid=blockIdx.x;
  if(bid<1536){
    int i = bid*256 + threadIdx.x;          // n8 index, total 393216
    int seg, j=i;
    if(j>=196608){
      if(j>=327680){ if(j>=360448){seg=9;j-=360448;} else {seg=8;j-=327680;} }
      else if(j>=262144){seg=7;j-=262144;}
      else {seg=6;j-=196608;}
    } else { seg=j>>15; j&=32767; }
    const float* src=s.p[seg];
    f32x4 a=*(const f32x4*)&src[(size_t)j*8];
    f32x4 b=*(const f32x4*)&src[(size_t)j*8+4];
    short8 o;
    #pragma unroll
    for(int qq=0;qq<4;++qq){ o[qq]=(short)f2b(a[qq]); o[4+qq]=(short)f2b(b[qq]); }
    *(short8*)&dst[(size_t)i*8]=o;
  } else {
    int bb=bid-1536;                        // 0..31
    int c = (bb&1)*256 + threadIdx.x;
    int r0 = (bb>>1)*124;
    float sum=0.f, sq=0.f;
    for(int r=r0;r<r0+124;++r){ float v=q[(size_t)r*Cn+c]; sum+=v; sq+=v*v; }
    ps [(bb>>1)*Cn+c]=sum;
    psq[(bb>>1)*Cn+c]=sq;
  }
}

__global__ __launch_bounds__(512) void k_bn1_final(const float* __restrict__ ps,
    const float* __restrict__ psq, const float* __restrict__ g,
    const float* __restrict__ b, float* __restrict__ scale, float* __restrict__ shift){
  int c = threadIdx.x;
  float s=0.f, sq=0.f;
  for(int i=0;i<16;++i){ s+=ps[i*Cn+c]; sq+=psq[i*Cn+c]; }
  float m = s/(float)Rn;
  float v = sq/(float)Rn - m*m;
  float rs = rsqrtf(v+EPSf);
  float sc = rs*g[c];
  scale[c]=sc; shift[c]=b[c]-m*sc;
}

// ---------------- fused BN + QKV projections (grid.z selects q/k/v) ------------
__global__ __launch_bounds__(256) void k_qkv(
    const float* __restrict__ q, const float* __restrict__ scale,
    const float* __restrict__ shift,
    const u16* __restrict__ W0, const u16* __restrict__ W1, const u16* __restrict__ W2,
    u16* __restrict__ o0, u16* __restrict__ o1v, u16* __restrict__ o2v)
{
  __shared__ u16 As[64][72];
  __shared__ u16 Ws[64][72];
  const int z=blockIdx.z;
  const u16* W = (z==0)?W0:((z==1)?W1:W2);
  u16* out     = (z==0)?o0:((z==1)?o1v:o2v);
  const int t=threadIdx.x, w=t>>6, l=t&63;
  const int m0=blockIdx.x*64, n0=blockIdx.y*64;
  const int lr=l&15, lk=(l>>4)*8;
  f32x4 zero={0.f,0.f,0.f,0.f};
  f32x4 acc[4];
  #pragma unroll
  for(int i=0;i<4;++i) acc[i]=zero;
  const int row0=t>>3, c8=(t&7)*8;
  for(int k0=0;k0<Cn;k0+=64){
    f32x4 sc0=*(const f32x4*)&scale[k0+c8], sc1=*(const f32x4*)&scale[k0+c8+4];
    f32x4 sh0=*(const f32x4*)&shift[k0+c8], sh1=*(const f32x4*)&shift[k0+c8+4];
    f32x4 x00=*(const f32x4*)&q[(size_t)(m0+row0   )*Cn+k0+c8];
    f32x4 x01=*(const f32x4*)&q[(size_t)(m0+row0   )*Cn+k0+c8+4];
    f32x4 x10=*(const f32x4*)&q[(size_t)(m0+32+row0)*Cn+k0+c8];
    f32x4 x11=*(const f32x4*)&q[(size_t)(m0+32+row0)*Cn+k0+c8+4];
    short8 a0,a1;
    #pragma unroll
    for(int j=0;j<4;++j){
      a0[j]  =(short)f2b(fmaf(x00[j],sc0[j],sh0[j]));
      a0[4+j]=(short)f2b(fmaf(x01[j],sc1[j],sh1[j]));
      a1[j]  =(short)f2b(fmaf(x10[j],sc0[j],sh0[j]));
      a1[4+j]=(short)f2b(fmaf(x11[j],sc1[j],sh1[j]));
    }
    short8 w0=*(const short8*)&W[(size_t)(n0+row0   )*Cn + k0 + c8];
    short8 w1=*(const short8*)&W[(size_t)(n0+32+row0)*Cn + k0 + c8];
    __syncthreads();
    *(short8*)&As[row0   ][c8]=a0;
    *(short8*)&As[32+row0][c8]=a1;
    *(short8*)&Ws[row0   ][c8]=w0;
    *(short8*)&Ws[32+row0][c8]=w1;
    __syncthreads();
    #pragma unroll
    for(int ks=0;ks<64;ks+=32){
      short8 af=*(const short8*)&As[w*16+lr][ks+lk];
      #pragma unroll
      for(int nf=0;nf<4;++nf){
        short8 bf=*(const short8*)&Ws[nf*16+lr][ks+lk];
        acc[nf]=mfma16(af,bf,acc[nf]);
      }
    }
  }
  const int r0=w*16+(l>>4)*4;
  #pragma unroll
  for(int nf=0;nf<4;++nf){
    const int n=n0+nf*16+lr;
    #pragma unroll
    for(int r=0;r<4;++r){
      const int m=m0+r0+r;
      out[(size_t)m*Cn+n]=f2b(acc[nf][r]);
    }
  }
}

// ---------------- generic 64x64-tile GEMM: out = A * W^T (+bias)(+res) ----------------
template<bool F32OUT, bool RES32>
__global__ __launch_bounds__(256) void k_gemm64(
    const u16* __restrict__ A, const u16* __restrict__ W,
    const float* __restrict__ bias, const void* __restrict__ res,
    void* __restrict__ outv, int M, int N, int K)
{
  __shared__ u16 As[64][72];
  __shared__ u16 Ws[64][72];
  const int t=threadIdx.x, w=t>>6, l=t&63;
  const int m0=blockIdx.x*64, n0=blockIdx.y*64;
  const int lr=l&15, lk=(l>>4)*8;
  f32x4 zero={0.f,0.f,0.f,0.f};
  f32x4 acc[4];
  #pragma unroll
  for(int i=0;i<4;++i) acc[i]=zero;
  const int row0=t>>3, c8=(t&7)*8;
  for(int k0=0;k0<K;k0+=64){
    short8 a0=*(const short8*)&A[(size_t)(m0+row0   )*K + k0 + c8];
    short8 a1=*(const short8*)&A[(size_t)(m0+32+row0)*K + k0 + c8];
    short8 w0=*(const short8*)&W[(size_t)(n0+row0   )*K + k0 + c8];
    short8 w1=*(const short8*)&W[(size_t)(n0+32+row0)*K + k0 + c8];
    __syncthreads();
    *(short8*)&As[row0   ][c8]=a0;
    *(short8*)&As[32+row0][c8]=a1;
    *(short8*)&Ws[row0   ][c8]=w0;
    *(short8*)&Ws[32+row0][c8]=w1;
    __syncthreads();
    #pragma unroll
    for(int ks=0;ks<64;ks+=32){
      short8 af=*(const short8*)&As[w*16+lr][ks+lk];
      #pragma unroll
      for(int nf=0;nf<4;++nf){
        short8 bf=*(const short8*)&Ws[nf*16+lr][ks+lk];
        acc[nf]=mfma16(af,bf,acc[nf]);
      }
    }
  }
  const int r0=w*16+(l>>4)*4;
  #pragma unroll
  for(int nf=0;nf<4;++nf){
    const int n=n0+nf*16+lr;
    float bv = bias? bias[n] : 0.f;
    #pragma unroll
    for(int r=0;r<4;++r){
      const int m=m0+r0+r;
      float vv=acc[nf][r]+bv;
      if(res){
        if(RES32) vv += ((const float*)res)[(size_t)m*N+n];
        else      vv += b2f(((const u16*)res)[(size_t)m*N+n]);
      }
      if(F32OUT) ((float*)outv)[(size_t)m*N+n]=vv;
      else       ((u16*)outv)[(size_t)m*N+n]=f2b(vv);
    }
  }
}

// ---------------- SA energy: per (b,h) 31x31 = q[31x64] * k[31x64]^T ----------------
__global__ __launch_bounds__(64) void k_energy1(const u16* __restrict__ q,
    const u16* __restrict__ k, float* __restrict__ e1){
  __shared__ u16 qs[32][72];
  __shared__ u16 ks_[32][72];
  const int bh=blockIdx.x, b=bh>>3, h=bh&7;
  const int t=threadIdx.x, l=t;
  #pragma unroll
  for(int i=0;i<4;++i){
    int flat=i*64+t; int row=flat>>3, c8=(flat&7)*8;
    short8 zq={0,0,0,0,0,0,0,0}, zk={0,0,0,0,0,0,0,0};
    if(row<31){
      zq=*(const short8*)&q[(size_t)(b*31+row)*Cn + h*64 + c8];
      zk=*(const short8*)&k[(size_t)(b*31+row)*Cn + h*64 + c8];
    }
    *(short8*)&qs [row][c8]=zq;
    *(short8*)&ks_[row][c8]=zk;
  }
  __syncthreads();
  const int lr=l&15, lk=(l>>4)*8;
  f32x4 zero={0.f,0.f,0.f,0.f};
  f32x4 acc[2][2];
  acc[0][0]=zero; acc[0][1]=zero; acc[1][0]=zero; acc[1][1]=zero;
  #pragma unroll
  for(int ks=0;ks<64;ks+=32){
    short8 a0=*(const short8*)&qs [lr   ][ks+lk];
    short8 a1=*(const short8*)&qs [16+lr][ks+lk];
    short8 b0=*(const short8*)&ks_[lr   ][ks+lk];
    short8 b1=*(const short8*)&ks_[16+lr][ks+lk];
    acc[0][0]=mfma16(a0,b0,acc[0][0]);
    acc[0][1]=mfma16(a0,b1,acc[0][1]);
    acc[1][0]=mfma16(a1,b0,acc[1][0]);
    acc[1][1]=mfma16(a1,b1,acc[1][1]);
  }
  const int r0=(l>>4)*4;
  #pragma unroll
  for(int i=0;i<2;++i)
    #pragma unroll
    for(int j=0;j<2;++j)
      #pragma unroll
      for(int r=0;r<4;++r){
        int qi=i*16+r0+r, ki=j*16+lr;
        if(qi<31 && ki<31) e1[(size_t)bh*961 + qi*31 + ki]=acc[i][j][r];
      }
}

// ---------------- BN over (B,H) on energy positions p=0..960 ----------------
__global__ __launch_bounds__(256) void k_bn2_partial(const float* __restrict__ e1,
    float* __restrict__ ps, float* __restrict__ psq){
  int p=blockIdx.x*256+threadIdx.x;
  if(p>=961) return;
  int r0=blockIdx.y*64;
  float s=0.f, sq=0.f;
  for(int r=r0;r<r0+64;++r){ float v=e1[(size_t)r*961+p]; s+=v; sq+=v*v; }
  ps [blockIdx.y*961+p]=s;
  psq[blockIdx.y*961+p]=sq;
}
__global__ __launch_bounds__(1024) void k_bn2_final(const float* __restrict__ ps,
    const float* __restrict__ psq, float* __restrict__ mu2, float* __restrict__ rstd2){
  int p=threadIdx.x; if(p>=961) return;
  float s=0.f, sq=0.f;
  for(int i=0;i<8;++i){ s+=ps[i*961+p]; sq+=psq[i*961+p]; }
  float m=s/512.f, v=sq/512.f-m*m;
  mu2[p]=m; rstd2[p]=rsqrtf(v+EPSf);
}

// ---------------- fused SA softmax (BN2-applied) + PV, one block per (b,h) --------
__global__ __launch_bounds__(64) void k_smpv(const float* __restrict__ e1,
    const float* __restrict__ mu2, const float* __restrict__ rstd2,
    const float* __restrict__ g2, const float* __restrict__ bb2,
    const u16* __restrict__ v, u16* __restrict__ o1){
  __shared__ u16 at[32][40];   // softmax probs, bf16
  __shared__ u16 vs[64][40];   // transposed V: vs[dh][kv]
  const int bh=blockIdx.x, b=bh>>3, h=bh&7;
  const int l=threadIdx.x;
  for(int kv=0;kv<31;++kv) vs[l][kv]=v[(size_t)(b*31+kv)*Cn + h*64 + l];
  vs[l][31]=0;
  if(l<31){
    const float* er=e1+(size_t)bh*961 + l*31;
    float lg[31]; float mx=-1e30f;
    #pragma unroll
    for(int kk=0;kk<31;++kk){
      int p=l*31+kk;
      float en=(er[kk]-mu2[p])*rstd2[p]*g2[p]+bb2[p];
      lg[kk]=en*INV_SCALE;
      mx=fmaxf(mx,lg[kk]);
    }
    float s=0.f;
    #pragma unroll
    for(int kk=0;kk<31;++kk){ lg[kk]=__expf(lg[kk]-mx); s+=lg[kk]; }
    float inv=1.f/s;
    #pragma unroll
    for(int kk=0;kk<31;++kk) at[l][kk]=f2b(lg[kk]*inv);
    at[l][31]=0;
  } else if(l==31){
    #pragma unroll
    for(int kk=0;kk<32;++kk) at[31][kk]=0;
  }
  __syncthreads();
  const int lr=l&15, lk=(l>>4)*8;
  f32x4 zero={0.f,0.f,0.f,0.f};
  f32x4 acc[2][4];
  #pragma unroll
  for(int i=0;i<2;++i)
    #pragma unroll
    for(int nf=0;nf<4;++nf) acc[i][nf]=zero;
  short8 a0=*(const short8*)&at[lr   ][lk];
  short8 a1=*(const short8*)&at[16+lr][lk];
  #pragma unroll
  for(int nf=0;nf<4;++nf){
    short8 bf=*(const short8*)&vs[nf*16+lr][lk];
    acc[0][nf]=mfma16(a0,bf,acc[0][nf]);
    acc[1][nf]=mfma16(a1,bf,acc[1][nf]);
  }
  const int r0=(l>>4)*4;
  #pragma unroll
  for(int i=0;i<2;++i)
    #pragma unroll
    for(int nf=0;nf<4;++nf)
      #pragma unroll
      for(int r=0;r<4;++r){
        int qi=i*16+r0+r;
        if(qi<31){
          int dh=nf*16+lr;
          o1[(size_t)(b*31+qi)*Cn + h*64 + dh]=f2b(acc[i][nf][r]);
        }
      }
}

// ---------------- row LayerNorm (optionally + SiLU), wave per row ----------------
template<int Wd, bool SILU>
__global__ __launch_bounds__(256) void k_ln(const u16* __restrict__ x,
    const float* __restrict__ g, const float* __restrict__ b, u16* __restrict__ out){
  const int w=threadIdx.x>>6, l=threadIdx.x&63;
  const int row=blockIdx.x*4+w;
  constexpr int NC=Wd/512;
  float v[NC*8];
  #pragma unroll
  for(int i=0;i<NC;++i){
    short8 s=*(const short8*)&x[(size_t)row*Wd + i*512 + l*8];
    #pragma unroll
    for(int j=0;j<8;++j) v[i*8+j]=b2f((u16)s[j]);
  }
  float s1=0.f, s2=0.f;
  #pragma unroll
  for(int e=0;e<NC*8;++e){ s1+=v[e]; s2+=v[e]*v[e]; }
  #pragma unroll
  for(int off=1;off<64;off<<=1){ s1+=__shfl_xor(s1,off,64); s2+=__shfl_xor(s2,off,64); }
  float m=s1/(float)Wd, var=s2/(float)Wd-m*m, rs=rsqrtf(var+EPSf);
  #pragma unroll
  for(int i=0;i<NC;++i){
    short8 o;
    #pragma unroll
    for(int j=0;j<8;++j){
      int c=i*512+l*8+j;
      float y=(v[i*8+j]-m)*rs*g[c]+b[c];
      if(SILU) y=y/(1.f+__expf(-y));
      o[j]=(short)f2b(y);
    }
    *(short8*)&out[(size_t)row*Wd + i*512 + l*8]=o;
  }
}

// ---------------- CA step 1: qk = q2_h (31x64) . Wk_h (64x512), Wk bf16 ----
__global__ __launch_bounds__(256) void k_qk(const u16* __restrict__ q2,
    const u16* __restrict__ Wk, u16* __restrict__ qk){
  __shared__ u16 qs[32][72];
  __shared__ u16 bt[128][72];    // bt[c][d] = Wk[h*64+d][nc+c]
  const int bh=blockIdx.x, b=bh>>3, h=bh&7;
  const int t=threadIdx.x, w=t>>6, l=t&63;
  {
    int row=t>>3, c8=(t&7)*8;
    short8 z={0,0,0,0,0,0,0,0};
    if(row<31) z=*(const short8*)&q2[(size_t)(b*31+row)*Cn + h*64 + c8];
    *(short8*)&qs[row][c8]=z;
  }
  const int lr=l&15, lk=(l>>4)*8;
  const int r0=(l>>4)*4;
  for(int nc=0;nc<512;nc+=128){
    __syncthreads();
    #pragma unroll
    for(int i=0;i<4;++i){
      int g=i*256+t;             // 0..1023
      int d=g>>4, c8=(g&15)*8;
      short8 s=*(const short8*)&Wk[(size_t)(h*64+d)*Cn + nc + c8];
      #pragma unroll
      for(int jj=0;jj<8;++jj) bt[c8+jj][d]=(u16)s[jj];
    }
    __syncthreads();
    f32x4 zero={0.f,0.f,0.f,0.f};
    f32x4 acc[2][2];
    acc[0][0]=zero; acc[0][1]=zero; acc[1][0]=zero; acc[1][1]=zero;
    #pragma unroll
    for(int ks=0;ks<64;ks+=32){
      short8 a0=*(const short8*)&qs[lr   ][ks+lk];
      short8 a1=*(const short8*)&qs[16+lr][ks+lk];
      #pragma unroll
      for(int nf=0;nf<2;++nf){
        short8 bf=*(const short8*)&bt[w*32+nf*16+lr][ks+lk];
        acc[0][nf]=mfma16(a0,bf,acc[0][nf]);
        acc[1][nf]=mfma16(a1,bf,acc[1][nf]);
      }
    }
    #pragma unroll
    for(int i=0;i<2;++i)
      #pragma unroll
      for(int nf=0;nf<2;++nf)
        #pragma unroll
        for(int r=0;r<4;++r){
          int qi=i*16+r0+r;
          if(qi<31)
            qk[((size_t)b*HRn + h*31 + qi)*Cn + nc + w*32 + nf*16 + lr]=f2b(acc[i][nf][r]);
        }
  }
}

// ---------------- CA step 2: e2(fp32) = qk . ctx^T ; exports ctxb bf16,
//                  P=exp(e2*s) bf16 into pb, partial denoms into psca.
//                  XCD-swizzled + LDS-only barriers. Pad-68 LDS -> 3 blocks/CU. ----
__global__ __launch_bounds__(512) void k_e2big(const u16* __restrict__ qk,
    const float* __restrict__ ctx, float* __restrict__ e2, u16* __restrict__ ctxb,
    u16* __restrict__ pb, float* __restrict__ psca){
  __shared__ u16 As[256][68];
  __shared__ u16 Bs[128][68];
  // XCD swizzle (T1): nwg=1024, cpx=128; swz=(bid%8)*128+bid/8 (bijective)
  const int bid = blockIdx.x + 16*blockIdx.y;
  const int swz = (bid&7)*128 + (bid>>3);
  const int b   = swz>>4;
  const int tb  = (swz&15)*128;
  const int t=threadIdx.x, w=t>>6, l=t&63;
  const int lr=l&15, lk=(l>>4)*8;
  const int wr=(w>>1)*64, wc=(w&1)*64;
  f32x4 zero={0.f,0.f,0.f,0.f};
  f32x4 acc[4][4];
  #pragma unroll
  for(int i=0;i<4;++i)
    #pragma unroll
    for(int j=0;j<4;++j) acc[i][j]=zero;

  const int arow[4]={ (0*512+t)>>3, (1*512+t)>>3, (2*512+t)>>3, (3*512+t)>>3 };
  const int ac8=(t&7)*8;
  const int brow=t>>4, bc4=(t&15)*4;     // 512 threads -> rows 0..31 per i-chunk
  short8 areg[4];
  f32x4  breg[4];
  auto loadK=[&](int k0){
    #pragma unroll
    for(int i=0;i<4;++i){
      short8 z={0,0,0,0,0,0,0,0};
      if(arow[i]<HRn) z=*(const short8*)&qk[((size_t)b*HRn+arow[i])*Cn + k0 + ac8];
      areg[i]=z;
    }
    #pragma unroll
    for(int i=0;i<4;++i)
      breg[i]=*(const f32x4*)&ctx[((size_t)b*Tn + tb + i*32+brow)*Cn + k0 + bc4];
  };
  loadK(0);
  for(int k0=0;k0<512;k0+=64){
    barrier_lgkm();
    #pragma unroll
    for(int i=0;i<4;++i) *(short8*)&As[arow[i]][ac8]=areg[i];
    #pragma unroll
    for(int i=0;i<4;++i){
      short4v o;
      #pragma unroll
      for(int jj=0;jj<4;++jj) o[jj]=(short)f2b(breg[i][jj]);
      *(short4v*)&Bs[i*32+brow][bc4]=o;
      *(short4v*)&ctxb[((size_t)b*Tn + tb + i*32+brow)*Cn + k0 + bc4]=o;
    }
    barrier_lgkm();
    if(k0+64<512) loadK(k0+64);
    #pragma unroll
    for(int ks=0;ks<64;ks+=32){
      short8 af[4], bf[4];
      #pragma unroll
      for(int i=0;i<4;++i){
        af[i]=*(const short8*)&As[wr+i*16+lr][ks+lk];
        bf[i]=*(const short8*)&Bs[wc+i*16+lr][ks+lk];
      }
      #pragma unroll
      for(int i=0;i<4;++i)
        #pragma unroll
        for(int j=0;j<4;++j)
          acc[i][j]=mfma16(af[i],bf[j],acc[i][j]);
    }
  }
  const int r0=(l>>4)*4;
  #pragma unroll
  for(int i=0;i<4;++i)
    #pragma unroll
    for(int r=0;r<4;++r){
      int rm=wr+i*16+r0+r;
      float psum=0.f;
      #pragma unroll
      for(int j=0;j<4;++j){
        float vv=acc[i][j][r];
        if(rm<HRn){
          size_t col = tb + wc + j*16 + lr;
          e2[((size_t)b*HRn+rm)*Tn + col]=vv;
          float p=__expf(vv*INV_SCALE);
          pb[((size_t)b*256+rm)*Tn + col]=f2b(p);
          psum+=p;
        }
      }
      // reduce over the 16 lanes (lr) that share this row
      psum+=__shfl_xor(psum,1,64);
      psum+=__shfl_xor(psum,2,64);
      psum+=__shfl_xor(psum,4,64);
      psum+=__shfl_xor(psum,8,64);
      if(rm<HRn && lr==0)
        psca[((size_t)b*HRn+rm)*32 + (tb>>7)*2 + (wc>>6)]=psum;
    }
}

// ---------------- reduce 32 partials per row -> denom st[row] ----------------
__global__ __launch_bounds__(256) void k_castred(const float* __restrict__ psca,
    float* __restrict__ st){
  int i=blockIdx.x*256+threadIdx.x;   // 0..15871
  if(i>=BHn*31) return;
  float s=0.f;
  #pragma unroll
  for(int j=0;j<32;++j) s+=psca[(size_t)i*32+j];
  st[i]=s;
}

// ---------------- CA step 3: o2t = P . ctxb, XCD-swizzled + LDS-only barriers ----
__global__ __launch_bounds__(512) void k_pv2(const u16* __restrict__ pb,
    const u16* __restrict__ ctxb, const float* __restrict__ st,
    u16* __restrict__ o2t){
  __shared__ u16 As[128][72];
  __shared__ u16 Bs[128][76];
  // XCD swizzle (T1): nwg=512, cpx=64; swz=(bid%8)*64+bid/8 (bijective)
  const int bid = blockIdx.x + 4*(blockIdx.y + 2*blockIdx.z);
  const int swz = (bid&7)*64 + (bid>>3);
  const int b   = swz>>3;
  const int m0  = ((swz>>2)&1)*128;
  const int n0  = (swz&3)*128;
  const int t=threadIdx.x, w=t>>6, l=t&63;
  const int lr=l&15, lk=(l>>4)*8;
  const int wm=(w>>2)*64, wn=(w&3)*32;
  f32x4 zero={0.f,0.f,0.f,0.f};
  f32x4 acc[4][2];
  #pragma unroll
  for(int i=0;i<4;++i){ acc[i][0]=zero; acc[i][1]=zero; }
  const int arow=t>>3, ac8=(t&7)*8;     // A staging (2 iters)
  const int bc=t&127, bq=(t>>7)*4;      // B staging: column bc, quads bq..bq+3
  short8 areg[2];
  u16 breg[16];
  auto loadK=[&](int kb){
    #pragma unroll
    for(int i=0;i<2;++i)
      areg[i]=*(const short8*)&pb[((size_t)b*256 + m0 + arow+i*64)*Tn + kb + ac8];
    #pragma unroll
    for(int i=0;i<4;++i){
      int kt0=(bq+i)*4;
      #pragma unroll
      for(int jj=0;jj<4;++jj)
        breg[i*4+jj]=ctxb[((size_t)b*Tn + kb + kt0 + jj)*Cn + n0 + bc];
    }
  };
  loadK(0);
  for(int kb=0;kb<Tn;kb+=64){
    barrier_lgkm();
    #pragma unroll
    for(int i=0;i<2;++i) *(short8*)&As[arow+i*64][ac8]=areg[i];
    #pragma unroll
    for(int i=0;i<4;++i){
      short4v o;
      #pragma unroll
      for(int jj=0;jj<4;++jj) o[jj]=(short)breg[i*4+jj];
      *(short4v*)&Bs[bc][(bq+i)*4]=o;
    }
    barrier_lgkm();
    if(kb+64<Tn) loadK(kb+64);
    #pragma unroll
    for(int ks=0;ks<64;ks+=32){
      short8 af[4], bf[2];
      #pragma unroll
      for(int i=0;i<4;++i)
        af[i]=*(const short8*)&As[wm+i*16+lr][ks+lk];
      #pragma unroll
      for(int j=0;j<2;++j){
        const u16* p=&Bs[wn+j*16+lr][ks+lk];
        short4v lo=*(const short4v*)p;
        short4v hi=*(const short4v*)(p+4);
        short8 bb;
        #pragma unroll
        for(int jj=0;jj<4;++jj){ bb[jj]=lo[jj]; bb[4+jj]=hi[jj]; }
        bf[j]=bb;
      }
      #pragma unroll
      for(int i=0;i<4;++i)
        #pragma unroll
        for(int j=0;j<2;++j)
          acc[i][j]=mfma16(af[i],bf[j],acc[i][j]);
    }
  }
  const int r0=(l>>4)*4;
  #pragma unroll
  for(int i=0;i<4;++i)
    #pragma unroll
    for(int j=0;j<2;++j)
      #pragma unroll
      for(int r=0;r<4;++r){
        int rm=m0+wm+i*16+r0+r;
        if(rm<HRn){
          float inv=1.f/st[(size_t)b*HRn+rm];
          o2t[((size_t)b*HRn+rm)*Cn + n0+wn+j*16+lr]=f2b(acc[i][j][r]*inv);
        }
      }
}

// ---------------- CA step 4: o2b = o2t_h (31x512) . Wv_h^T (64x512), Wv bf16 ------
__global__ __launch_bounds__(256) void k_o2proj(const u16* __restrict__ o2t,
    const u16* __restrict__ Wv, u16* __restrict__ o2b){
  __shared__ u16 As[32][72];
  __shared__ u16 Ws[64][72];
  const int bh=blockIdx.x, b=bh>>3, h=bh&7;
  const int t=threadIdx.x, w=t>>6, l=t&63;
  const int lr=l&15, lk=(l>>4)*8;
  f32x4 zero={0.f,0.f,0.f,0.f};
  f32x4 acc[2]; acc[0]=zero; acc[1]=zero;
  for(int k0=0;k0<512;k0+=64){
    __syncthreads();
    {
      int row=t>>3, c8=(t&7)*8;
      short8 z={0,0,0,0,0,0,0,0};
      if(row<31) z=*(const short8*)&o2t[((size_t)b*HRn + h*31 + row)*Cn + k0 + c8];
      *(short8*)&As[row][c8]=z;
    }
    #pragma unroll
    for(int i=0;i<2;++i){
      int g=i*256+t; int row=g>>3, c8=(g&7)*8;
      short8 s=*(const short8*)&Wv[(size_t)(h*64+row)*Cn + k0 + c8];
      *(short8*)&Ws[row][c8]=s;
    }
    __syncthreads();
    #pragma unroll
    for(int ks=0;ks<64;ks+=32){
      short8 a0=*(const short8*)&As[lr   ][ks+lk];
      short8 a1=*(const short8*)&As[16+lr][ks+lk];
      short8 bf=*(const short8*)&Ws[w*16+lr][ks+lk];
      acc[0]=mfma16(a0,bf,acc[0]);
      acc[1]=mfma16(a1,bf,acc[1]);
    }
  }
  const int r0=(l>>4)*4;
  #pragma unroll
  for(int i=0;i<2;++i)
    #pragma unroll
    for(int r=0;r<4;++r){
      int qi=i*16+r0+r;
      if(qi<31)
        o2b[((size_t)b*31+qi)*Cn + h*64 + w*16 + lr]=f2b(acc[i][r]);
    }
}

// =====================================================================
extern "C" void kernel_launch(void* const* d_in, const int* in_sizes, int n_in,
                              void* d_out, int out_size, void* d_ws, size_t ws_size,
                              hipStream_t stream){
  (void)out_size; (void)ws_size;
  float* outp=(float*)d_out;                 // out (B,S,C) fp32
  float* e2  =outp + (size_t)Rn*Cn;          // energy2 (B,H,S,CTX) fp32
  if(n_in<24 || in_sizes[0]!=Rn*Cn || in_sizes[1]!=Bn*Tn*Cn ||
     in_sizes[4]!=Cn*Cn || in_sizes[9]!=961 || in_sizes[20]!=2*Cn*Cn){
    k_badorder<<<1,64,0,stream>>>(outp);
    return;
  }
  const float* queries =(const float*)d_in[0];
  const float* contexts=(const float*)d_in[1];
  const float* sa_bn_g =(const float*)d_in[2];
  const float* sa_bn_b =(const float*)d_in[3];
  const float* sa_q_w  =(const float*)d_in[4];
  const float* sa_k_w  =(const float*)d_in[5];
  const float* sa_v_w  =(const float*)d_in[6];
  const float* sa_out_w=(const float*)d_in[7];
  const float* sa_out_b=(const float*)d_in[8];
  const float* sa_pre_g=(const float*)d_in[9];
  const float* sa_pre_b=(const float*)d_in[10];
  const float* ca_ln_g =(const float*)d_in[11];
  const float* ca_ln_b =(const float*)d_in[12];
  const float* ca_q_w  =(const float*)d_in[13];
  const float* ca_k_w  =(const float*)d_in[14];
  const float* ca_v_w  =(const float*)d_in[15];
  const float* ca_out_w=(const float*)d_in[16];
  const float* ca_out_b=(const float*)d_in[17];
  const float* ff_ln1_g=(const float*)d_in[18];
  const float* ff_ln1_b=(const float*)d_in[19];
  const float* ff_w1   =(const float*)d_in[20];
  const float* ff_ln2_g=(const float*)d_in[21];
  const float* ff_ln2_b=(const float*)d_in[22];
  const float* ff_w2   =(const float*)d_in[23];

  char* ws=(char*)d_ws;
  size_t off=0;
  auto alloc=[&](size_t bytes)->char*{
    char* p=ws+off; off=(off+bytes+255)&~(size_t)255; return p;
  };
  float* ps1  =(float*)alloc(16*Cn*4);
  float* psq1 =(float*)alloc(16*Cn*4);
  float* scale1=(float*)alloc(Cn*4);
  float* shift1=(float*)alloc(Cn*4);
  // weights bf16: MUST stay contiguous & in this order (k_cvtbn writes linearly)
  u16* w_sq=(u16*)alloc((size_t)Cn*Cn*2);
  u16* w_sk=(u16*)alloc((size_t)Cn*Cn*2);
  u16* w_sv=(u16*)alloc((size_t)Cn*Cn*2);
  u16* w_so=(u16*)alloc((size_t)Cn*Cn*2);
  u16* w_cq=(u16*)alloc((size_t)Cn*Cn*2);
  u16* w_co=(u16*)alloc((size_t)Cn*Cn*2);
  u16* w_f1=(u16*)alloc((size_t)2*Cn*Cn*2);
  u16* w_f2=(u16*)alloc((size_t)2*Cn*Cn*2);
  u16* w_ck=(u16*)alloc((size_t)Cn*Cn*2);
  u16* w_cv=(u16*)alloc((size_t)Cn*Cn*2);
  u16* qb  =(u16*)alloc((size_t)Rn*Cn*2);
  u16* kb  =(u16*)alloc((size_t)Rn*Cn*2);   // qb+kb contiguous (t1 alias)
  u16* vb  =(u16*)alloc((size_t)Rn*Cn*2);
  float* e1  =(float*)alloc((size_t)BHn*961*4);
  float* ps2 =(float*)alloc(8*961*4);
  float* psq2=(float*)alloc(8*961*4);
  float* mu2 =(float*)alloc(961*4);
  float* rstd2=(float*)alloc(961*4);
  u16* o1  =(u16*)alloc((size_t)Rn*Cn*2);
  u16* xsa =(u16*)alloc((size_t)Rn*Cn*2);
  u16* qn  =(u16*)alloc((size_t)Rn*Cn*2);
  u16* q2b =(u16*)alloc((size_t)Rn*Cn*2);
  u16* qk  =(u16*)alloc((size_t)Bn*HRn*Cn*2);   // 16.25 MB
  float* psca=(float*)alloc((size_t)BHn*31*32*4); // 2 MB partial denoms
  float* st=(float*)alloc((size_t)BHn*31*4);
  u16* o2b =(u16*)alloc((size_t)Rn*Cn*2);
  u16* xca =(u16*)alloc((size_t)Rn*Cn*2);
  u16* pb  =(u16*)alloc((size_t)Bn*256*Tn*2);   // 67 MB
  u16* ctxb=(u16*)alloc((size_t)Bn*Tn*Cn*2);    // 134 MB bf16 contexts
  // aliases (non-overlapping lifetimes):
  u16* o2t = qk;     // qk dead after k_e2big
  u16* f1  = o1;     // o1 dead after SA out-proj
  u16* t1  = qb;     // spans qb+kb, dead after k_energy1
  u16* f2  = vb;     // vb dead after k_smpv

  dim3 blk256(256), blk64(64), blk512(512);
  dim3 g64(Rn/64, Cn/64);     // (31, 8)

  // ---- weight converts + bn1 partial, one launch ----
  Src10 s10;
  s10.p[0]=sa_q_w; s10.p[1]=sa_k_w; s10.p[2]=sa_v_w; s10.p[3]=sa_out_w;
  s10.p[4]=ca_q_w; s10.p[5]=ca_out_w; s10.p[6]=ff_w1; s10.p[7]=ff_w2;
  s10.p[8]=ca_k_w; s10.p[9]=ca_v_w;
  k_cvtbn<<<1568,blk256,0,stream>>>(s10, w_sq, queries, ps1, psq1);

  // ---- Self-attention ----
  k_bn1_final<<<1,512,0,stream>>>(ps1,psq1,sa_bn_g,sa_bn_b,scale1,shift1);
  k_qkv<<<dim3(31,8,3),blk256,0,stream>>>(queries,scale1,shift1,w_sq,w_sk,w_sv,qb,kb,vb);
  k_energy1<<<BHn,blk64,0,stream>>>(qb,kb,e1);
  k_bn2_partial<<<dim3(4,8),blk256,0,stream>>>(e1,ps2,psq2);
  k_bn2_final<<<1,1024,0,stream>>>(ps2,psq2,mu2,rstd2);
  k_smpv<<<BHn,blk64,0,stream>>>(e1,mu2,rstd2,sa_pre_g,sa_pre_b,vb,o1);
  k_gemm64<false,true><<<g64,blk256,0,stream>>>(o1,w_so,sa_out_b,queries,xsa,Rn,Cn,Cn);

  // ---- Cross-attention (round-21 best schedule; e2big pad-68 for 3 blocks/CU) ----
  k_ln<512,false><<<Rn/4,blk256,0,stream>>>(xsa,ca_ln_g,ca_ln_b,qn);
  k_gemm64<false,false><<<g64,blk256,0,stream>>>(qn,w_cq,nullptr,nullptr,q2b,Rn,Cn,Cn);
  k_qk<<<BHn,blk256,0,stream>>>(q2b,w_ck,qk);
  k_e2big<<<dim3(Tn/128,Bn),blk512,0,stream>>>(qk,contexts,e2,ctxb,pb,psca);
  k_castred<<<62,blk256,0,stream>>>(psca,st);
  k_pv2<<<dim3(Cn/128,2,Bn),blk512,0,stream>>>(pb,ctxb,st,o2t);
  k_o2proj<<<BHn,blk256,0,stream>>>(o2t,w_cv,o2b);
  k_gemm64<false,false><<<g64,blk256,0,stream>>>(o2b,w_co,ca_out_b,xsa,xca,Rn,Cn,Cn);

  // ---- FFN ----
  k_ln<512,true><<<Rn/4,blk256,0,stream>>>(xca,ff_ln1_g,ff_ln1_b,f1);
  k_gemm64<false,false><<<dim3(Rn/64,1024/64),blk256,0,stream>>>(f1,w_f1,nullptr,nullptr,t1,Rn,1024,Cn);
  k_ln<1024,true><<<Rn/4,blk256,0,stream>>>(t1,ff_ln2_g,ff_ln2_b,f2);
  k_gemm64<true,false><<<g64,blk256,0,stream>>>(f2,w_f2,nullptr,xca,outp,Rn,Cn,1024);
}